// Round 1
// 220.244 us; speedup vs baseline: 1.1413x; 1.1413x over previous
//
#include <hip/hip_runtime.h>
#include <math.h>

#define HW 4096   // H*W = 64*64; B=4, C=64, H=W=64, L=4096

typedef short bf16x8 __attribute__((ext_vector_type(8)));
typedef float floatx4 __attribute__((ext_vector_type(4)));

__device__ __forceinline__ unsigned short f2bf_rne(float x) {
    unsigned int u = __float_as_uint(x);
    unsigned int r = (u + 0x7FFFu + ((u >> 16) & 1u)) >> 16;
    return (unsigned short)r;
}
__device__ __forceinline__ float bf2f(unsigned short h) {
    return __uint_as_float(((unsigned int)h) << 16);
}

// async global->LDS, 16 B per lane; LDS dest is wave-uniform base + lane*16.
__device__ __forceinline__ void gload_lds16(const void* gptr, void* lptr) {
    auto g = (const __attribute__((address_space(1))) unsigned int*)(unsigned long long)(gptr);
    auto l = (__attribute__((address_space(3))) unsigned int*)(unsigned int)(unsigned long long)(lptr);
    __builtin_amdgcn_global_load_lds(g, l, 16, 0, 0);
}

// ---------------- prep: split fp32 -> bf16 (hi,lo), transpose to [p][c], ------
// fused per-pixel squared norms. Aq[b][p] = [Qh|Qh|Ql], Bq[b][p] = [Kh|Kl|Kh]
// so a 192-dot gives QhKh + QhKl + QlKh ~= fp32 dot.
__global__ __launch_bounds__(256)
void prep_kernel(const float* __restrict__ Q, const float* __restrict__ K,
                 unsigned short* __restrict__ Aq, unsigned short* __restrict__ Bq,
                 float* __restrict__ pix2q, float* __restrict__ pix2k) {
    __shared__ float sT[64][65];
    const int tid = threadIdx.x;
    const int p0 = blockIdx.x * 64;
    const int b = blockIdx.y;
    const int pp = tid >> 2, qt = tid & 3;
    const size_t base = ((size_t)b * 4096 + p0 + pp) * 192;

#pragma unroll
    for (int it = 0; it < 16; ++it) {
        int idx = it * 256 + tid;
        int c = idx >> 6, x = idx & 63;
        sT[c][x] = Q[((size_t)b * 64 + c) * HW + p0 + x];
    }
    __syncthreads();
    {
        float sq = 0.f;
#pragma unroll
        for (int i = 0; i < 16; ++i) {
            int c = qt * 16 + i;
            float x = sT[c][pp];
            sq = fmaf(x, x, sq);
            unsigned short h = f2bf_rne(x);
            unsigned short l = f2bf_rne(x - bf2f(h));
            Aq[base + c] = h;
            Aq[base + 64 + c] = h;
            Aq[base + 128 + c] = l;
        }
        sq += __shfl_xor(sq, 1, 64);
        sq += __shfl_xor(sq, 2, 64);
        if (qt == 0) pix2q[(b << 12) + p0 + pp] = sq;
    }
    __syncthreads();

#pragma unroll
    for (int it = 0; it < 16; ++it) {
        int idx = it * 256 + tid;
        int c = idx >> 6, x = idx & 63;
        sT[c][x] = K[((size_t)b * 64 + c) * HW + p0 + x];
    }
    __syncthreads();
    {
        float sk = 0.f;
#pragma unroll
        for (int i = 0; i < 16; ++i) {
            int c = qt * 16 + i;
            float x = sT[c][pp];
            sk = fmaf(x, x, sk);
            unsigned short h = f2bf_rne(x);
            unsigned short l = f2bf_rne(x - bf2f(h));
            Bq[base + c] = h;
            Bq[base + 64 + c] = l;
            Bq[base + 128 + c] = h;
        }
        sk += __shfl_xor(sk, 1, 64);
        sk += __shfl_xor(sk, 2, 64);
        if (qt == 0) pix2k[(b << 12) + p0 + pp] = sk;
    }
}

// ---------------- patch reciprocal norms: 1/max(sqrt(3x3 box sum), 1e-12) ----
__global__ void patchnorm_kernel(const float* __restrict__ pix2q, const float* __restrict__ pix2k,
                                 float* __restrict__ rnq, float* __restrict__ rnk) {
    int idx = blockIdx.x * 256 + threadIdx.x;   // b*4096 + p
    int b = idx >> 12, p = idx & 4095;
    int py = p >> 6, px = p & 63;
    float sq = 0.f, sk = 0.f;
    for (int dy = -1; dy <= 1; ++dy)
        for (int dx = -1; dx <= 1; ++dx) {
            int yy = py + dy, xx = px + dx;
            if ((unsigned)yy < 64u && (unsigned)xx < 64u) {
                int o = (b << 12) + (yy << 6) + xx;
                sq += pix2q[o];
                sk += pix2k[o];
            }
        }
    rnq[idx] = 1.f / fmaxf(sqrtf(sq), 1e-12f);
    rnk[idx] = 1.f / fmaxf(sqrtf(sk), 1e-12f);
}

// ---------------- fused MFMA GEMM (K=576: y-3sum in K) + x-3sum + argmax -----
// Interior blocks: ring-chunk pipeline. The 256-row slab = 4 chunks of 64
// rows (8 KB/operand); chunk (seg,r) lives in slot r. 9 compute steps
// (seg,dy), each reading chunks {dy,dy+1}; next-seg chunk loads issued 1-2
// steps ahead with counted vmcnt (never a full drain except seg joins).
// Boundary blocks (~12%) take the legacy guarded 3-seg path.
// Epilogue: x-3sum + argmax per k-quarter, then LDS reduce of the 4
// quarters -> 32 partial slots per (b,q) instead of 128.
#define WAITV(n_) asm volatile("s_waitcnt vmcnt(" #n_ ")" ::: "memory")
#define PBAR(n_) do { WAITV(n_); __builtin_amdgcn_s_barrier(); \
                      asm volatile("" ::: "memory"); } while (0)

#define ISSUE_CHUNK(g_) do { \
    const int sg_ = (g_) >> 2, r_ = (g_) & 3; \
    _Pragma("unroll") \
    for (int it_ = 0; it_ < 2; ++it_) { \
        int s16_ = it_ * 256 + tid; \
        int rr_ = s16_ >> 3, pos_ = s16_ & 7, G_ = pos_ ^ (rr_ & 7); \
        gload_lds16(ab + (size_t)(r_ * 64 + rr_) * 384 + sg_ * 128 + G_ * 16, \
                    smem + ((r_ * 64 + rr_) * 8 + pos_) * 16); \
        gload_lds16(bb + (size_t)(r_ * 64 + rr_) * 384 + sg_ * 128 + G_ * 16, \
                    smem + 32768 + ((r_ * 64 + rr_) * 8 + pos_) * 16); \
    } \
} while (0)

#define MFMA_STEP(dy_) do { \
    _Pragma("unroll") \
    for (int kk = 0; kk < 2; ++kk) { \
        bf16x8 af[4], bfr[4]; \
        _Pragma("unroll") \
        for (int mt = 0; mt < 4; ++mt) { \
            int row = (dy_) * 64 + wm * 64 + mt * 16 + m15; \
            int pos = (kk * 4 + quad) ^ (row & 7); \
            af[mt] = *(const bf16x8*)(smem + (row * 8 + pos) * 16); \
        } \
        _Pragma("unroll") \
        for (int nt = 0; nt < 4; ++nt) { \
            int row = (dy_) * 64 + wn * 64 + nt * 16 + m15; \
            int pos = (kk * 4 + quad) ^ (row & 7); \
            bfr[nt] = *(const bf16x8*)(smem + 32768 + (row * 8 + pos) * 16); \
        } \
        __builtin_amdgcn_s_setprio(1); \
        _Pragma("unroll") \
        for (int mt = 0; mt < 4; ++mt) \
            _Pragma("unroll") \
            for (int nt = 0; nt < 4; ++nt) \
                acc[mt][nt] = __builtin_amdgcn_mfma_f32_16x16x32_bf16( \
                    af[mt], bfr[nt], acc[mt][nt], 0, 0, 0); \
        __builtin_amdgcn_s_setprio(0); \
    } \
} while (0)

__global__ __launch_bounds__(256, 2)
void gemm_fused_kernel(const unsigned short* __restrict__ Aq, const unsigned short* __restrict__ Bq,
                       const float* __restrict__ rnkA,
                       float* __restrict__ part_val, int* __restrict__ part_arg) {
    __shared__ __align__(16) char smem[65536];   // A ring 32K | B ring 32K; epilogue Csh[64][133]+aux
    const int tid = threadIdx.x;
    const int lane = tid & 63, wid = tid >> 6;
    const int m15 = lane & 15, quad = lane >> 4;
    const int wm = wid & 1, wn = wid >> 1;
    const int k0 = blockIdx.x * 128;
    const int q0 = blockIdx.y * 128;
    const int b = blockIdx.z;
    const char* Aqb = (const char*)(Aq + (size_t)b * 4096 * 192);
    const char* Bqb = (const char*)(Bq + (size_t)b * 4096 * 192);
    const bool aInt = (q0 >= 64) && (q0 <= 4096 - 192);   // A slab fully in-image
    const bool bInt = (k0 >= 64) && (k0 <= 4096 - 192);

    floatx4 acc[4][4];
#pragma unroll
    for (int i = 0; i < 4; ++i)
#pragma unroll
        for (int j = 0; j < 4; ++j) acc[i][j] = (floatx4)0.f;

    if (aInt && bInt) {
        // ---- pipelined interior path ----
        const char* ab = Aqb + (size_t)(q0 - 64) * 384;   // slab row 0
        const char* bb = Bqb + (size_t)(k0 - 64) * 384;
        // chunk g = seg*4 + r -> slot r; 4 gload_lds16 per thread per chunk (A+B).
        ISSUE_CHUNK(0); ISSUE_CHUNK(1); ISSUE_CHUNK(2); ISSUE_CHUNK(3);
        PBAR(8);                                MFMA_STEP(0);   // s0,dy0: chunks 0,1
        PBAR(4); ISSUE_CHUNK(4);                MFMA_STEP(1);   // s0,dy1: 1,2  (issue s1r0->slot0)
        PBAR(4); ISSUE_CHUNK(5);                MFMA_STEP(2);   // s0,dy2: 2,3  (issue s1r1->slot1)
        PBAR(0); ISSUE_CHUNK(6); ISSUE_CHUNK(7); MFMA_STEP(0);  // s1,dy0: 4,5  (issue s1r2/r3)
        PBAR(4); ISSUE_CHUNK(8);                MFMA_STEP(1);   // s1,dy1: 5,6  (issue s2r0)
        PBAR(4); ISSUE_CHUNK(9);                MFMA_STEP(2);   // s1,dy2: 6,7  (issue s2r1)
        PBAR(0); ISSUE_CHUNK(10); ISSUE_CHUNK(11); MFMA_STEP(0);// s2,dy0: 8,9  (issue s2r2/r3)
        PBAR(4);                                MFMA_STEP(1);   // s2,dy1: 9,10
        PBAR(0);                                MFMA_STEP(2);   // s2,dy2: 10,11
        __syncthreads();   // ring dead before epilogue overwrites
    } else {
        // ---- legacy guarded path (boundary blocks) ----
        for (int seg = 0; seg < 3; ++seg) {
            const char* abL = Aqb + (size_t)(q0 - 64) * 384 + seg * 128;
            const char* bbL = Bqb + (size_t)(k0 - 64) * 384 + seg * 128;
            if (aInt) {
#pragma unroll
                for (int it = 0; it < 8; ++it) {
                    int slot = it * 256 + tid;
                    int row = slot >> 3, pos = slot & 7;
                    int G = pos ^ (row & 7);
                    gload_lds16(abL + (size_t)row * 384 + G * 16, smem + slot * 16);
                }
            } else {
#pragma unroll
                for (int it = 0; it < 8; ++it) {
                    int slot = it * 256 + tid;
                    int row = slot >> 3, pos = slot & 7;
                    int G = pos ^ (row & 7);
                    uint4 v = make_uint4(0u, 0u, 0u, 0u);
                    if ((unsigned)(q0 - 64 + row) < 4096u)
                        v = *(const uint4*)(abL + (size_t)row * 384 + G * 16);
                    *(uint4*)(smem + slot * 16) = v;
                }
            }
            if (bInt) {
#pragma unroll
                for (int it = 0; it < 8; ++it) {
                    int slot = it * 256 + tid;
                    int row = slot >> 3, pos = slot & 7;
                    int G = pos ^ (row & 7);
                    gload_lds16(bbL + (size_t)row * 384 + G * 16, smem + 32768 + slot * 16);
                }
            } else {
#pragma unroll
                for (int it = 0; it < 8; ++it) {
                    int slot = it * 256 + tid;
                    int row = slot >> 3, pos = slot & 7;
                    int G = pos ^ (row & 7);
                    uint4 v = make_uint4(0u, 0u, 0u, 0u);
                    if ((unsigned)(k0 - 64 + row) < 4096u)
                        v = *(const uint4*)(bbL + (size_t)row * 384 + G * 16);
                    *(uint4*)(smem + 32768 + slot * 16) = v;
                }
            }
            __syncthreads();
            MFMA_STEP(0); MFMA_STEP(1); MFMA_STEP(2);
            __syncthreads();
        }
    }

    // ---- epilogue: two 64-row phases; x-3sum + max/argmax over the 128-k tile,
    // then cross-quarter LDS reduce -> one partial per (block, q) ----
    float* Csh = (float*)smem;               // [64][133]
    float* bvs = (float*)(smem + 34816);     // [4][64]
    int*   bas = (int*)(smem + 35840);       // [4][64]
    const int q_l = tid & 63;
    const int qr = tid >> 6;                 // k-quarter (0..3), one per wave
    const int c0 = qr * 32;
    const float4 zero4 = make_float4(0.f, 0.f, 0.f, 0.f);

#pragma unroll
    for (int h = 0; h < 2; ++h) {
        if (h) __syncthreads();              // phase-0 readers done before overwrite
        if (wm == h) {
#pragma unroll
            for (int mt = 0; mt < 4; ++mt)
#pragma unroll
                for (int nt = 0; nt < 4; ++nt)
#pragma unroll
                    for (int j = 0; j < 4; ++j)
                        Csh[(mt * 16 + quad * 4 + j) * 133 + wn * 64 + nt * 16 + m15] =
                            acc[mt][nt][j];
        }
        __syncthreads();

        const bool qm = q_l > 0;             // qx>0: diag- allowed
        const bool qp = q_l < 63;            // qx<63: diag+ allowed
        const float* rC = Csh + q_l * 133;
        const float* rM = Csh + (q_l - 1) * 133;
        const float* rP = Csh + (q_l + 1) * 133;
        float4 prevm = (qm && c0 > 0) ? *(const float4*)&rM[c0 - 4] : zero4;
        float4 rpj   = qp ? *(const float4*)&rP[c0] : zero4;
        float bv = -INFINITY;
        int ba = 0;
#pragma unroll
        for (int j = 0; j < 8; ++j) {
            int c = c0 + 4 * j;
            float4 cen = *(const float4*)&rC[c];
            float4 rm4 = qm ? *(const float4*)&rM[c] : zero4;
            float4 rp1 = (qp && (c + 4) < 128) ? *(const float4*)&rP[c + 4] : zero4;
            float4 o;
            o.x = cen.x + (((c & 63) != 0) ? prevm.w : 0.f) + rpj.y;
            o.y = cen.y + rm4.x + rpj.z;
            o.z = cen.z + rm4.y + rpj.w;
            o.w = cen.w + rm4.z + ((((c + 3) & 63) != 63) ? rp1.x : 0.f);
            float4 rk = *(const float4*)&rnkA[(b << 12) + k0 + c];
            // ascending k + strict > = first-occurrence argmax
            float v0 = o.x * rk.x; if (v0 > bv) { bv = v0; ba = k0 + c + 0; }
            float v1 = o.y * rk.y; if (v1 > bv) { bv = v1; ba = k0 + c + 1; }
            float v2 = o.z * rk.z; if (v2 > bv) { bv = v2; ba = k0 + c + 2; }
            float v3 = o.w * rk.w; if (v3 > bv) { bv = v3; ba = k0 + c + 3; }
            prevm = rm4;
            rpj = rp1;
        }
        bvs[(qr << 6) + q_l] = bv;
        bas[(qr << 6) + q_l] = ba;
        __syncthreads();
        if (tid < 64) {
            float v = bvs[tid];
            int a = bas[tid];
#pragma unroll
            for (int s = 1; s < 4; ++s) {    // ascending quarter = ascending k
                float v2 = bvs[(s << 6) + tid];
                if (v2 > v) { v = v2; a = bas[(s << 6) + tid]; }
            }
            int q = q0 + h * 64 + tid;
            part_val[(((b << 5) + blockIdx.x) << 12) + q] = v;
            part_arg[(((b << 5) + blockIdx.x) << 12) + q] = a;
        }
    }
}

// ---------------- gather + fold, fused combine (32 k-slot partials) ----------
// Combines partials for arg rows y-1..y+1, writes S for row y, then
// T[c,y,x] = (1/9) sum_{dy,dx} Vzp[c, a(q)+d], q=(y-dy,x-dx)
__global__ __launch_bounds__(256)
void gatherS_kernel(const float* __restrict__ V,
                    const float* __restrict__ part_val, const int* __restrict__ part_arg,
                    const float* __restrict__ rnqA,
                    float* __restrict__ S_out, float* __restrict__ T_out) {
    __shared__ int sArg[192];
    const int y = blockIdx.x, b = blockIdx.y;
    const int tid = threadIdx.x;
    if (tid < 192) {
        int r = tid >> 6, x = tid & 63;
        int yy = y - 1 + r;
        int a = 0;
        if ((unsigned)yy < 64u) {
            int base = (b << 17) + (yy << 6) + x;   // part[(b*32+s)][q]
            float bv = -INFINITY; int ba = 0;
#pragma unroll 8
            for (int s = 0; s < 32; ++s) {   // ascending s = ascending k: first max wins
                float v = part_val[base + (s << 12)];
                int aa = part_arg[base + (s << 12)];
                if (v > bv) { bv = v; ba = aa; }
            }
            a = ba;
            if (r == 1) {
                int idx = (b << 12) + (yy << 6) + x;
                S_out[idx] = bv * rnqA[idx];
            }
        }
        sArg[tid] = a;
    }
    __syncthreads();

    const int x = tid & 63, cq = tid >> 6;
    int off[9];
#pragma unroll
    for (int t = 0; t < 9; ++t) {
        int dy = t / 3 - 1, dx = t % 3 - 1;
        int qy = y - dy, qx = x - dx;
        int o = -1;
        if ((unsigned)qy < 64u && (unsigned)qx < 64u) {
            int a = sArg[(1 - dy) * 64 + qx];
            int sy = (a >> 6) + dy, sx = (a & 63) + dx;
            if ((unsigned)sy < 64u && (unsigned)sx < 64u) o = (sy << 6) + sx;
        }
        off[t] = o;
    }
    const float* Vb = V + (size_t)b * 64 * HW;
    float* Tb = T_out + (size_t)b * 64 * HW + (y << 6) + x;
    for (int ci = 0; ci < 16; ++ci) {
        int c = cq * 16 + ci;
        const float* Vc = Vb + (size_t)c * HW;
        float acc = 0.f;
#pragma unroll
        for (int t = 0; t < 9; ++t)
            acc += (off[t] >= 0) ? Vc[off[t]] : 0.f;
        Tb[(size_t)c * HW] = acc * (1.f / 9.f);
    }
}

extern "C" void kernel_launch(void* const* d_in, const int* in_sizes, int n_in,
                              void* d_out, int out_size, void* d_ws, size_t ws_size,
                              hipStream_t stream) {
    const float* V = (const float*)d_in[0];
    const float* K = (const float*)d_in[1];
    const float* Q = (const float*)d_in[2];
    float* S_out = (float*)d_out;            // 4*4096
    float* T_out = S_out + 4 * HW;           // 4*64*4096

    char* ws = (char*)d_ws;
    float* pix2q = (float*)(ws + 0);                 // 64 KB
    float* pix2k = (float*)(ws + 65536);
    float* rnq   = (float*)(ws + 131072);
    float* rnk   = (float*)(ws + 196608);
    float* part_val = (float*)(ws + 262144);         // 4*32*4096 f = 2 MB used
    int*   part_arg = (int*)(ws + 8650752);          // 2 MB used
    unsigned short* Aq = (unsigned short*)(ws + 17039360);   // 4*4096*192 bf16 = 6 MiB
    unsigned short* Bq = (unsigned short*)(ws + 23330816);   // 6 MiB

    prep_kernel<<<dim3(64, 4), 256, 0, stream>>>(Q, K, Aq, Bq, pix2q, pix2k);
    patchnorm_kernel<<<64, 256, 0, stream>>>(pix2q, pix2k, rnq, rnk);
    gemm_fused_kernel<<<dim3(32, 32, 4), 256, 0, stream>>>(Aq, Bq, rnk, part_val, part_arg);
    gatherS_kernel<<<dim3(64, 4), 256, 0, stream>>>(V, part_val, part_arg, rnq, S_out, T_out);
}

// Round 2
// 211.417 us; speedup vs baseline: 1.1890x; 1.0418x over previous
//
#include <hip/hip_runtime.h>
#include <math.h>

#define HW 4096   // H*W = 64*64; B=4, C=64, H=W=64, L=4096

typedef short bf16x8 __attribute__((ext_vector_type(8)));
typedef float floatx4 __attribute__((ext_vector_type(4)));

__device__ __forceinline__ unsigned short f2bf_rne(float x) {
    unsigned int u = __float_as_uint(x);
    unsigned int r = (u + 0x7FFFu + ((u >> 16) & 1u)) >> 16;
    return (unsigned short)r;
}
__device__ __forceinline__ float bf2f(unsigned short h) {
    return __uint_as_float(((unsigned int)h) << 16);
}

// async global->LDS, 16 B per lane; LDS dest is wave-uniform base + lane*16.
__device__ __forceinline__ void gload_lds16(const void* gptr, void* lptr) {
    auto g = (const __attribute__((address_space(1))) unsigned int*)(unsigned long long)(gptr);
    auto l = (__attribute__((address_space(3))) unsigned int*)(unsigned int)(unsigned long long)(lptr);
    __builtin_amdgcn_global_load_lds(g, l, 16, 0, 0);
}

// ---------------- prep: split fp32 -> bf16 (hi,lo), transpose to [p][c], ------
// fused per-pixel squared norms. Aq[b][p] = [Qh|Qh|Ql], Bq[b][p] = [Kh|Kl|Kh]
// so a 192-dot gives QhKh + QhKl + QlKh ~= fp32 dot.
__global__ __launch_bounds__(256)
void prep_kernel(const float* __restrict__ Q, const float* __restrict__ K,
                 unsigned short* __restrict__ Aq, unsigned short* __restrict__ Bq,
                 float* __restrict__ pix2q, float* __restrict__ pix2k) {
    __shared__ float sT[64][65];
    const int tid = threadIdx.x;
    const int p0 = blockIdx.x * 64;
    const int b = blockIdx.y;
    const int pp = tid >> 2, qt = tid & 3;
    const size_t base = ((size_t)b * 4096 + p0 + pp) * 192;

#pragma unroll
    for (int it = 0; it < 16; ++it) {
        int idx = it * 256 + tid;
        int c = idx >> 6, x = idx & 63;
        sT[c][x] = Q[((size_t)b * 64 + c) * HW + p0 + x];
    }
    __syncthreads();
    {
        float sq = 0.f;
#pragma unroll
        for (int i = 0; i < 16; ++i) {
            int c = qt * 16 + i;
            float x = sT[c][pp];
            sq = fmaf(x, x, sq);
            unsigned short h = f2bf_rne(x);
            unsigned short l = f2bf_rne(x - bf2f(h));
            Aq[base + c] = h;
            Aq[base + 64 + c] = h;
            Aq[base + 128 + c] = l;
        }
        sq += __shfl_xor(sq, 1, 64);
        sq += __shfl_xor(sq, 2, 64);
        if (qt == 0) pix2q[(b << 12) + p0 + pp] = sq;
    }
    __syncthreads();

#pragma unroll
    for (int it = 0; it < 16; ++it) {
        int idx = it * 256 + tid;
        int c = idx >> 6, x = idx & 63;
        sT[c][x] = K[((size_t)b * 64 + c) * HW + p0 + x];
    }
    __syncthreads();
    {
        float sk = 0.f;
#pragma unroll
        for (int i = 0; i < 16; ++i) {
            int c = qt * 16 + i;
            float x = sT[c][pp];
            sk = fmaf(x, x, sk);
            unsigned short h = f2bf_rne(x);
            unsigned short l = f2bf_rne(x - bf2f(h));
            Bq[base + c] = h;
            Bq[base + 64 + c] = l;
            Bq[base + 128 + c] = h;
        }
        sk += __shfl_xor(sk, 1, 64);
        sk += __shfl_xor(sk, 2, 64);
        if (qt == 0) pix2k[(b << 12) + p0 + pp] = sk;
    }
}

// ---------------- patch reciprocal norms: 1/max(sqrt(3x3 box sum), 1e-12) ----
__global__ void patchnorm_kernel(const float* __restrict__ pix2q, const float* __restrict__ pix2k,
                                 float* __restrict__ rnq, float* __restrict__ rnk) {
    int idx = blockIdx.x * 256 + threadIdx.x;   // b*4096 + p
    int b = idx >> 12, p = idx & 4095;
    int py = p >> 6, px = p & 63;
    float sq = 0.f, sk = 0.f;
    for (int dy = -1; dy <= 1; ++dy)
        for (int dx = -1; dx <= 1; ++dx) {
            int yy = py + dy, xx = px + dx;
            if ((unsigned)yy < 64u && (unsigned)xx < 64u) {
                int o = (b << 12) + (yy << 6) + xx;
                sq += pix2q[o];
                sk += pix2k[o];
            }
        }
    rnq[idx] = 1.f / fmaxf(sqrtf(sq), 1e-12f);
    rnk[idx] = 1.f / fmaxf(sqrtf(sk), 1e-12f);
}

// ---------------- fused MFMA GEMM (K=576: y-3sum in K) + x-3sum + argmax -----
// Data identity: Aq = [Qh|Qh|Ql], Bq = [Kh|Kl|Kh].  Segs ordered
// s0 = Qh.Kh, s1 = Qh.Kl (A frags REUSED FROM REGISTERS), s2 = Ql.Kh.
// LDS: A region 4 slots (32K: Ah0-3, then Al reuses dead slots), B region
// 5 slots (40K ring: Bh0-3, Bl0-3, Bh'0-3).  20 staged chunks instead of 24;
// every vmcnt wait targets a chunk issued >=2 steps earlier; no mid drains.
// XCD-chunked swizzle makes each XCD's staging ~2MB (L2-resident).
#define WAITV(n_) asm volatile("s_waitcnt vmcnt(" #n_ ")" ::: "memory")
#define PBAR(n_) do { WAITV(n_); __builtin_amdgcn_s_barrier(); \
                      asm volatile("" ::: "memory"); } while (0)

#define ISSUE_A(c_, sg_, slot_) do { \
    const char* g_ = Aqb + (size_t)(q0 - 64 + (c_) * 64) * 384 + (sg_) * 128; \
    gload_lds16(g_ + g0off, smem + (slot_) * 8192 + l0off); \
    gload_lds16(g_ + g1off, smem + (slot_) * 8192 + l1off); \
} while (0)
#define ISSUE_B(c_, sg_, slot_) do { \
    const char* g_ = Bqb + (size_t)(k0 - 64 + (c_) * 64) * 384 + (sg_) * 128; \
    gload_lds16(g_ + g0off, smemB + (slot_) * 8192 + l0off); \
    gload_lds16(g_ + g1off, smemB + (slot_) * 8192 + l1off); \
} while (0)

#define MM16(af_, bfr_) do { \
    __builtin_amdgcn_s_setprio(1); \
    _Pragma("unroll") \
    for (int mt = 0; mt < 4; ++mt) \
        _Pragma("unroll") \
        for (int nt = 0; nt < 4; ++nt) \
            acc[mt][nt] = __builtin_amdgcn_mfma_f32_16x16x32_bf16( \
                (af_)[mt], (bfr_)[nt], acc[mt][nt], 0, 0, 0); \
    __builtin_amdgcn_s_setprio(0); \
} while (0)

// seg0: read A (and cache to afc) + B from LDS
#define STEP_S0(D_) do { \
    const char* As_ = smem + (wm + (D_)) * 8192; \
    const char* Bs_ = smemB + (wn + (D_)) * 8192; \
    _Pragma("unroll") \
    for (int kk = 0; kk < 2; ++kk) { \
        const int pk_ = kk ? posK1 : posK0; \
        bf16x8 bfr[4]; \
        _Pragma("unroll") \
        for (int mt = 0; mt < 4; ++mt) \
            afc[(D_)][kk][mt] = *(const bf16x8*)(As_ + mt * 2048 + rowB + pk_); \
        _Pragma("unroll") \
        for (int nt = 0; nt < 4; ++nt) \
            bfr[nt] = *(const bf16x8*)(Bs_ + nt * 2048 + rowB + pk_); \
        MM16(afc[(D_)][kk], bfr); \
    } \
} while (0)

// seg1: A from register cache, B (Kl) from LDS slot {4,0,1,2}[wn+D]
#define STEP_S1(D_) do { \
    const int xb_ = wn + (D_); \
    const char* Bs_ = smemB + (xb_ ? (xb_ - 1) : 4) * 8192; \
    _Pragma("unroll") \
    for (int kk = 0; kk < 2; ++kk) { \
        const int pk_ = kk ? posK1 : posK0; \
        bf16x8 bfr[4]; \
        _Pragma("unroll") \
        for (int nt = 0; nt < 4; ++nt) \
            bfr[nt] = *(const bf16x8*)(Bs_ + nt * 2048 + rowB + pk_); \
        MM16(afc[(D_)][kk], bfr); \
    } \
} while (0)

// seg2: A (Ql) from slot {3,0,1,2}[wm+D], B (Kh') from slot {3,4,0,1}[wn+D]
#define STEP_S2(D_) do { \
    const int xa_ = wm + (D_), xb_ = wn + (D_); \
    const char* As_ = smem + (xa_ ? (xa_ - 1) : 3) * 8192; \
    const char* Bs_ = smemB + (xb_ < 2 ? xb_ + 3 : xb_ - 2) * 8192; \
    _Pragma("unroll") \
    for (int kk = 0; kk < 2; ++kk) { \
        const int pk_ = kk ? posK1 : posK0; \
        bf16x8 af[4], bfr[4]; \
        _Pragma("unroll") \
        for (int mt = 0; mt < 4; ++mt) \
            af[mt] = *(const bf16x8*)(As_ + mt * 2048 + rowB + pk_); \
        _Pragma("unroll") \
        for (int nt = 0; nt < 4; ++nt) \
            bfr[nt] = *(const bf16x8*)(Bs_ + nt * 2048 + rowB + pk_); \
        MM16(af, bfr); \
    } \
} while (0)

__global__ __launch_bounds__(256, 2)
void gemm_fused_kernel(const unsigned short* __restrict__ Aq, const unsigned short* __restrict__ Bq,
                       const float* __restrict__ rnkA,
                       float* __restrict__ part_val, int* __restrict__ part_arg) {
    __shared__ __align__(16) char smem[73728];   // A 4x8K | B 5x8K; epilogue Csh[64][133]+aux
    char* const smemB = smem + 32768;
    const int tid = threadIdx.x;
    const int lane = tid & 63, wid = tid >> 6;
    const int m15 = lane & 15, quad = lane >> 4;
    const int wm = wid & 1, wn = wid >> 1;
    // XCD-chunked swizzle: per-b 1024 wgs; XCD x owns contiguous original
    // range [x*128,(x+1)*128) = 4 q-tiles x all 32 k-tiles (~2MB < 4MB L2).
    const int f = blockIdx.x + (blockIdx.y << 5);
    const int o = ((f & 7) << 7) + (f >> 3);
    const int kt = o & 31, qt = o >> 5;
    const int k0 = kt << 7;
    const int q0 = qt << 7;
    const int b = blockIdx.z;
    const char* Aqb = (const char*)(Aq + (size_t)b * 4096 * 192);
    const char* Bqb = (const char*)(Bq + (size_t)b * 4096 * 192);
    const bool aInt = (q0 >= 64) && (q0 <= 4096 - 192);   // A slab fully in-image
    const bool bInt = (k0 >= 64) && (k0 <= 4096 - 192);

    // per-thread staging offsets (chunk = 64 rows x 8 pos x 16B; pos^=(row&7))
    const int rr0 = tid >> 3, ps = tid & 7;
    const int g0off = rr0 * 384 + (ps ^ (rr0 & 7)) * 16;
    const int l0off = tid * 16;
    const int rr1 = (256 + tid) >> 3;
    const int g1off = rr1 * 384 + (ps ^ (rr1 & 7)) * 16;
    const int l1off = (256 + tid) * 16;
    // per-thread fragment-read offsets
    const int rowB = m15 * 128;
    const int posK0 = (quad ^ (m15 & 7)) * 16;
    const int posK1 = ((4 + quad) ^ (m15 & 7)) * 16;

    floatx4 acc[4][4];
#pragma unroll
    for (int i = 0; i < 4; ++i)
#pragma unroll
        for (int j = 0; j < 4; ++j) acc[i][j] = (floatx4)0.f;

    bf16x8 afc[3][2][4];   // seg0 A-fragment cache, reused in seg1

    if (aInt && bInt) {
        // prologue: Ah0-3 -> A0-3, Bh0-3 -> B0-3, Bl0 -> B4 (9 chunks, 18 loads)
        ISSUE_A(0, 0, 0); ISSUE_A(1, 0, 1); ISSUE_B(0, 0, 0); ISSUE_B(1, 0, 1);
        ISSUE_A(2, 0, 2); ISSUE_B(2, 0, 2); ISSUE_A(3, 0, 3); ISSUE_B(3, 0, 3);
        ISSUE_B(0, 1, 4);
        PBAR(10);                                   STEP_S0(0);   // t0
        PBAR(6);  ISSUE_B(1, 1, 0); ISSUE_A(1, 2, 0); STEP_S0(1); // t1: Bl1,Al1
        PBAR(6);  ISSUE_B(2, 1, 1); ISSUE_A(2, 2, 1); STEP_S0(2); // t2: Bl2,Al2
        PBAR(6);  ISSUE_B(3, 1, 2); ISSUE_B(0, 0, 3);             // t3: Bl3,Bh'0
                  ISSUE_A(0, 2, 3); ISSUE_A(3, 2, 2); STEP_S1(0); //     Al0,Al3
        PBAR(10); ISSUE_B(1, 0, 4);                 STEP_S1(1);   // t4: Bh'1
        PBAR(8);  ISSUE_B(2, 0, 0);                 STEP_S1(2);   // t5: Bh'2
        PBAR(2);  ISSUE_B(3, 0, 1);                 STEP_S2(0);   // t6: Bh'3
        PBAR(2);                                    STEP_S2(1);   // t7
        PBAR(0);                                    STEP_S2(2);   // t8
        __syncthreads();   // ring dead before epilogue overwrites
    } else {
        // ---- legacy guarded path (boundary blocks): stage full slabs per seg ----
        for (int seg = 0; seg < 3; ++seg) {
            const char* abL = Aqb + (size_t)(q0 - 64) * 384 + seg * 128;
            const char* bbL = Bqb + (size_t)(k0 - 64) * 384 + seg * 128;
            if (aInt) {
#pragma unroll
                for (int it = 0; it < 8; ++it) {
                    int slot = it * 256 + tid;
                    int row = slot >> 3, pos = slot & 7;
                    int G = pos ^ (row & 7);
                    gload_lds16(abL + (size_t)row * 384 + G * 16, smem + slot * 16);
                }
            } else {
#pragma unroll
                for (int it = 0; it < 8; ++it) {
                    int slot = it * 256 + tid;
                    int row = slot >> 3, pos = slot & 7;
                    int G = pos ^ (row & 7);
                    uint4 v = make_uint4(0u, 0u, 0u, 0u);
                    if ((unsigned)(q0 - 64 + row) < 4096u)
                        v = *(const uint4*)(abL + (size_t)row * 384 + G * 16);
                    *(uint4*)(smem + slot * 16) = v;
                }
            }
            if (bInt) {
#pragma unroll
                for (int it = 0; it < 8; ++it) {
                    int slot = it * 256 + tid;
                    int row = slot >> 3, pos = slot & 7;
                    int G = pos ^ (row & 7);
                    gload_lds16(bbL + (size_t)row * 384 + G * 16, smemB + slot * 16);
                }
            } else {
#pragma unroll
                for (int it = 0; it < 8; ++it) {
                    int slot = it * 256 + tid;
                    int row = slot >> 3, pos = slot & 7;
                    int G = pos ^ (row & 7);
                    uint4 v = make_uint4(0u, 0u, 0u, 0u);
                    if ((unsigned)(k0 - 64 + row) < 4096u)
                        v = *(const uint4*)(bbL + (size_t)row * 384 + G * 16);
                    *(uint4*)(smemB + slot * 16) = v;
                }
            }
            __syncthreads();
            STEP_S0(0); STEP_S0(1); STEP_S0(2);
            __syncthreads();
        }
    }

    // ---- epilogue: two 64-row phases; x-3sum + max/argmax over the 128-k tile,
    // then cross-quarter LDS reduce -> one partial per (block, q) ----
    float* Csh = (float*)smem;               // [64][133]
    float* bvs = (float*)(smem + 34816);     // [4][64]
    int*   bas = (int*)(smem + 35840);       // [4][64]
    const int q_l = tid & 63;
    const int qr = tid >> 6;                 // k-quarter (0..3), one per wave
    const int c0 = qr * 32;
    const float4 zero4 = make_float4(0.f, 0.f, 0.f, 0.f);

#pragma unroll
    for (int h = 0; h < 2; ++h) {
        if (h) __syncthreads();              // phase-0 readers done before overwrite
        if (wm == h) {
#pragma unroll
            for (int mt = 0; mt < 4; ++mt)
#pragma unroll
                for (int nt = 0; nt < 4; ++nt)
#pragma unroll
                    for (int j = 0; j < 4; ++j)
                        Csh[(mt * 16 + quad * 4 + j) * 133 + wn * 64 + nt * 16 + m15] =
                            acc[mt][nt][j];
        }
        __syncthreads();

        const bool qm = q_l > 0;             // qx>0: diag- allowed
        const bool qp = q_l < 63;            // qx<63: diag+ allowed
        const float* rC = Csh + q_l * 133;
        const float* rM = Csh + (q_l - 1) * 133;
        const float* rP = Csh + (q_l + 1) * 133;
        float4 prevm = (qm && c0 > 0) ? *(const float4*)&rM[c0 - 4] : zero4;
        float4 rpj   = qp ? *(const float4*)&rP[c0] : zero4;
        float bv = -INFINITY;
        int ba = 0;
#pragma unroll
        for (int j = 0; j < 8; ++j) {
            int c = c0 + 4 * j;
            float4 cen = *(const float4*)&rC[c];
            float4 rm4 = qm ? *(const float4*)&rM[c] : zero4;
            float4 rp1 = (qp && (c + 4) < 128) ? *(const float4*)&rP[c + 4] : zero4;
            float4 o4;
            o4.x = cen.x + (((c & 63) != 0) ? prevm.w : 0.f) + rpj.y;
            o4.y = cen.y + rm4.x + rpj.z;
            o4.z = cen.z + rm4.y + rpj.w;
            o4.w = cen.w + rm4.z + ((((c + 3) & 63) != 63) ? rp1.x : 0.f);
            float4 rk = *(const float4*)&rnkA[(b << 12) + k0 + c];
            // ascending k + strict > = first-occurrence argmax
            float v0 = o4.x * rk.x; if (v0 > bv) { bv = v0; ba = k0 + c + 0; }
            float v1 = o4.y * rk.y; if (v1 > bv) { bv = v1; ba = k0 + c + 1; }
            float v2 = o4.z * rk.z; if (v2 > bv) { bv = v2; ba = k0 + c + 2; }
            float v3 = o4.w * rk.w; if (v3 > bv) { bv = v3; ba = k0 + c + 3; }
            prevm = rm4;
            rpj = rp1;
        }
        bvs[(qr << 6) + q_l] = bv;
        bas[(qr << 6) + q_l] = ba;
        __syncthreads();
        if (tid < 64) {
            float v = bvs[tid];
            int a = bas[tid];
#pragma unroll
            for (int s = 1; s < 4; ++s) {    // ascending quarter = ascending k
                float v2 = bvs[(s << 6) + tid];
                if (v2 > v) { v = v2; a = bas[(s << 6) + tid]; }
            }
            int q = q0 + h * 64 + tid;
            part_val[(((b << 5) + kt) << 12) + q] = v;
            part_arg[(((b << 5) + kt) << 12) + q] = a;
        }
    }
}

// ---------------- gather + fold, fused combine (32 k-slot partials) ----------
// Combines partials for arg rows y-1..y+1, writes S for row y, then
// T[c,y,x] = (1/9) sum_{dy,dx} Vzp[c, a(q)+d], q=(y-dy,x-dx)
__global__ __launch_bounds__(256)
void gatherS_kernel(const float* __restrict__ V,
                    const float* __restrict__ part_val, const int* __restrict__ part_arg,
                    const float* __restrict__ rnqA,
                    float* __restrict__ S_out, float* __restrict__ T_out) {
    __shared__ int sArg[192];
    const int y = blockIdx.x, b = blockIdx.y;
    const int tid = threadIdx.x;
    if (tid < 192) {
        int r = tid >> 6, x = tid & 63;
        int yy = y - 1 + r;
        int a = 0;
        if ((unsigned)yy < 64u) {
            int base = (b << 17) + (yy << 6) + x;   // part[(b*32+s)][q]
            float bv = -INFINITY; int ba = 0;
#pragma unroll 8
            for (int s = 0; s < 32; ++s) {   // ascending s = ascending k: first max wins
                float v = part_val[base + (s << 12)];
                int aa = part_arg[base + (s << 12)];
                if (v > bv) { bv = v; ba = aa; }
            }
            a = ba;
            if (r == 1) {
                int idx = (b << 12) + (yy << 6) + x;
                S_out[idx] = bv * rnqA[idx];
            }
        }
        sArg[tid] = a;
    }
    __syncthreads();

    const int x = tid & 63, cq = tid >> 6;
    int off[9];
#pragma unroll
    for (int t = 0; t < 9; ++t) {
        int dy = t / 3 - 1, dx = t % 3 - 1;
        int qy = y - dy, qx = x - dx;
        int o = -1;
        if ((unsigned)qy < 64u && (unsigned)qx < 64u) {
            int a = sArg[(1 - dy) * 64 + qx];
            int sy = (a >> 6) + dy, sx = (a & 63) + dx;
            if ((unsigned)sy < 64u && (unsigned)sx < 64u) o = (sy << 6) + sx;
        }
        off[t] = o;
    }
    const float* Vb = V + (size_t)b * 64 * HW;
    float* Tb = T_out + (size_t)b * 64 * HW + (y << 6) + x;
    for (int ci = 0; ci < 16; ++ci) {
        int c = cq * 16 + ci;
        const float* Vc = Vb + (size_t)c * HW;
        float acc = 0.f;
#pragma unroll
        for (int t = 0; t < 9; ++t)
            acc += (off[t] >= 0) ? Vc[off[t]] : 0.f;
        Tb[(size_t)c * HW] = acc * (1.f / 9.f);
    }
}

extern "C" void kernel_launch(void* const* d_in, const int* in_sizes, int n_in,
                              void* d_out, int out_size, void* d_ws, size_t ws_size,
                              hipStream_t stream) {
    const float* V = (const float*)d_in[0];
    const float* K = (const float*)d_in[1];
    const float* Q = (const float*)d_in[2];
    float* S_out = (float*)d_out;            // 4*4096
    float* T_out = S_out + 4 * HW;           // 4*64*4096

    char* ws = (char*)d_ws;
    float* pix2q = (float*)(ws + 0);                 // 64 KB
    float* pix2k = (float*)(ws + 65536);
    float* rnq   = (float*)(ws + 131072);
    float* rnk   = (float*)(ws + 196608);
    float* part_val = (float*)(ws + 262144);         // 4*32*4096 f = 2 MB used
    int*   part_arg = (int*)(ws + 8650752);          // 2 MB used
    unsigned short* Aq = (unsigned short*)(ws + 17039360);   // 4*4096*192 bf16 = 6 MiB
    unsigned short* Bq = (unsigned short*)(ws + 23330816);   // 6 MiB

    prep_kernel<<<dim3(64, 4), 256, 0, stream>>>(Q, K, Aq, Bq, pix2q, pix2k);
    patchnorm_kernel<<<64, 256, 0, stream>>>(pix2q, pix2k, rnq, rnk);
    gemm_fused_kernel<<<dim3(32, 32, 4), 256, 0, stream>>>(Aq, Bq, rnk, part_val, part_arg);
    gatherS_kernel<<<dim3(64, 4), 256, 0, stream>>>(V, part_val, part_arg, rnq, S_out, T_out);
}

// Round 3
// 204.738 us; speedup vs baseline: 1.2278x; 1.0326x over previous
//
#include <hip/hip_runtime.h>
#include <math.h>

#define HW 4096   // H*W = 64*64; B=4, C=64, H=W=64, L=4096

typedef short bf16x8 __attribute__((ext_vector_type(8)));
typedef float floatx4 __attribute__((ext_vector_type(4)));
typedef unsigned short u16x8 __attribute__((ext_vector_type(8)));

__device__ __forceinline__ unsigned short f2bf_rne(float x) {
    unsigned int u = __float_as_uint(x);
    unsigned int r = (u + 0x7FFFu + ((u >> 16) & 1u)) >> 16;
    return (unsigned short)r;
}
__device__ __forceinline__ float bf2f(unsigned short h) {
    return __uint_as_float(((unsigned int)h) << 16);
}

// async global->LDS, 16 B per lane; LDS dest is wave-uniform base + lane*16.
__device__ __forceinline__ void gload_lds16(const void* gptr, void* lptr) {
    auto g = (const __attribute__((address_space(1))) unsigned int*)(unsigned long long)(gptr);
    auto l = (__attribute__((address_space(3))) unsigned int*)(unsigned int)(unsigned long long)(lptr);
    __builtin_amdgcn_global_load_lds(g, l, 16, 0, 0);
}

// ---------------- prep: split fp32 -> bf16 (hi,lo), transpose to [p][c], ------
// fused per-pixel squared norms. Aq[b][p] = [Qh|Qh|Ql], Bq[b][p] = [Kh|Kl|Kh]
// so a 192-dot gives QhKh + QhKl + QlKh ~= fp32 dot.  All Aq/Bq stores are
// 16B vector stores (u16x8).
__global__ __launch_bounds__(256)
void prep_kernel(const float* __restrict__ Q, const float* __restrict__ K,
                 unsigned short* __restrict__ Aq, unsigned short* __restrict__ Bq,
                 float* __restrict__ pix2q, float* __restrict__ pix2k) {
    __shared__ float sT[64][65];
    const int tid = threadIdx.x;
    const int p0 = blockIdx.x * 64;
    const int b = blockIdx.y;
    const int pp = tid >> 2, qt = tid & 3;
    const size_t base = ((size_t)b * 4096 + p0 + pp) * 192;

#pragma unroll
    for (int it = 0; it < 16; ++it) {
        int idx = it * 256 + tid;
        int c = idx >> 6, x = idx & 63;
        sT[c][x] = Q[((size_t)b * 64 + c) * HW + p0 + x];
    }
    __syncthreads();
    {
        float sq = 0.f;
        u16x8 hv[2], lv[2];
#pragma unroll
        for (int g = 0; g < 2; ++g)
#pragma unroll
            for (int j = 0; j < 8; ++j) {
                int c = qt * 16 + g * 8 + j;
                float x = sT[c][pp];
                sq = fmaf(x, x, sq);
                unsigned short h = f2bf_rne(x);
                hv[g][j] = h;
                lv[g][j] = f2bf_rne(x - bf2f(h));
            }
        sq += __shfl_xor(sq, 1, 64);
        sq += __shfl_xor(sq, 2, 64);
        if (qt == 0) pix2q[(b << 12) + p0 + pp] = sq;
#pragma unroll
        for (int g = 0; g < 2; ++g) {
            int co = qt * 16 + g * 8;
            *(u16x8*)(Aq + base + co)       = hv[g];
            *(u16x8*)(Aq + base + 64 + co)  = hv[g];
            *(u16x8*)(Aq + base + 128 + co) = lv[g];
        }
    }
    __syncthreads();

#pragma unroll
    for (int it = 0; it < 16; ++it) {
        int idx = it * 256 + tid;
        int c = idx >> 6, x = idx & 63;
        sT[c][x] = K[((size_t)b * 64 + c) * HW + p0 + x];
    }
    __syncthreads();
    {
        float sk = 0.f;
        u16x8 hv[2], lv[2];
#pragma unroll
        for (int g = 0; g < 2; ++g)
#pragma unroll
            for (int j = 0; j < 8; ++j) {
                int c = qt * 16 + g * 8 + j;
                float x = sT[c][pp];
                sk = fmaf(x, x, sk);
                unsigned short h = f2bf_rne(x);
                hv[g][j] = h;
                lv[g][j] = f2bf_rne(x - bf2f(h));
            }
        sk += __shfl_xor(sk, 1, 64);
        sk += __shfl_xor(sk, 2, 64);
        if (qt == 0) pix2k[(b << 12) + p0 + pp] = sk;
#pragma unroll
        for (int g = 0; g < 2; ++g) {
            int co = qt * 16 + g * 8;
            *(u16x8*)(Bq + base + co)       = hv[g];
            *(u16x8*)(Bq + base + 64 + co)  = lv[g];
            *(u16x8*)(Bq + base + 128 + co) = hv[g];
        }
    }
}

// ---------------- patch reciprocal norms: 1/max(sqrt(3x3 box sum), 1e-12) ----
__global__ void patchnorm_kernel(const float* __restrict__ pix2q, const float* __restrict__ pix2k,
                                 float* __restrict__ rnq, float* __restrict__ rnk) {
    int idx = blockIdx.x * 256 + threadIdx.x;   // b*4096 + p
    int b = idx >> 12, p = idx & 4095;
    int py = p >> 6, px = p & 63;
    float sq = 0.f, sk = 0.f;
    for (int dy = -1; dy <= 1; ++dy)
        for (int dx = -1; dx <= 1; ++dx) {
            int yy = py + dy, xx = px + dx;
            if ((unsigned)yy < 64u && (unsigned)xx < 64u) {
                int o = (b << 12) + (yy << 6) + xx;
                sq += pix2q[o];
                sk += pix2k[o];
            }
        }
    rnq[idx] = 1.f / fmaxf(sqrtf(sq), 1e-12f);
    rnk[idx] = 1.f / fmaxf(sqrtf(sk), 1e-12f);
}

// ---------------- fused MFMA GEMM (K=576: y-3sum in K) + x-3sum + argmax -----
// Slice identities: Aq=[Qh|Qh|Ql] (slice1==slice0), Bq=[Kh|Kl|Kh]
// (slice2==slice0). Step order (s0,s1,s2) per dy:
//   s0 = Qh.Kh : A,B from LDS; cache A frags->afc, B frags->bfc (1 dy live)
//   s1 = Qh.Kl : A = afc (no LDS), B = Bl from LDS
//   s2 = Ql.Kh : A = Al from LDS, B = bfc (no LDS, and Bh' NEVER STAGED)
// 16 staged chunks (vs 24 naive / 20 prev), 96 ds_read_b128/wave (vs 120).
// LDS: A 5 slots | B 5 slots = 80 KB -> 2 blocks/CU exactly.
// Ring schedule hand-verified: every vmcnt wait covers chunks issued >=1
// step earlier; every slot overwrite is after last-reader barrier + its
// gload completion forced by an earlier wait.
#define WAITV(n_) asm volatile("s_waitcnt vmcnt(" #n_ ")" ::: "memory")
#define PBAR(n_) do { WAITV(n_); __builtin_amdgcn_s_barrier(); \
                      asm volatile("" ::: "memory"); } while (0)

#define ISSUE_A(c_, sg_, slot_) do { \
    const char* g_ = Aqb + (size_t)(q0 - 64 + (c_) * 64) * 384 + (sg_) * 128; \
    gload_lds16(g_ + g0off, smem + (slot_) * 8192 + l0off); \
    gload_lds16(g_ + g1off, smem + (slot_) * 8192 + l1off); \
} while (0)
#define ISSUE_B(c_, sg_, slot_) do { \
    const char* g_ = Bqb + (size_t)(k0 - 64 + (c_) * 64) * 384 + (sg_) * 128; \
    gload_lds16(g_ + g0off, smemB + (slot_) * 8192 + l0off); \
    gload_lds16(g_ + g1off, smemB + (slot_) * 8192 + l1off); \
} while (0)

#define MM16(af_, bfr_) do { \
    __builtin_amdgcn_s_setprio(1); \
    _Pragma("unroll") \
    for (int mt = 0; mt < 4; ++mt) \
        _Pragma("unroll") \
        for (int nt = 0; nt < 4; ++nt) \
            acc[mt][nt] = __builtin_amdgcn_mfma_f32_16x16x32_bf16( \
                (af_)[mt], (bfr_)[nt], acc[mt][nt], 0, 0, 0); \
    __builtin_amdgcn_s_setprio(0); \
} while (0)

// s0: A slot (wm+D), B slot (wn+D); cache both fragment sets
#define STEP_S0(D_) do { \
    const char* As_ = smem + (wm + (D_)) * 8192; \
    const char* Bs_ = smemB + (wn + (D_)) * 8192; \
    _Pragma("unroll") \
    for (int kk = 0; kk < 2; ++kk) { \
        const int pk_ = kk ? posK1 : posK0; \
        _Pragma("unroll") \
        for (int mt = 0; mt < 4; ++mt) \
            afc[kk][mt] = *(const bf16x8*)(As_ + mt * 2048 + rowB + pk_); \
        _Pragma("unroll") \
        for (int nt = 0; nt < 4; ++nt) \
            bfc[kk][nt] = *(const bf16x8*)(Bs_ + nt * 2048 + rowB + pk_); \
        MM16(afc[kk], bfc[kk]); \
    } \
} while (0)

// s1: A from afc; B (Kl) slot {3,4,0,1}[wn+D]
#define STEP_S1(D_) do { \
    const int xb_ = wn + (D_); \
    const char* Bs_ = smemB + (xb_ < 2 ? xb_ + 3 : xb_ - 2) * 8192; \
    _Pragma("unroll") \
    for (int kk = 0; kk < 2; ++kk) { \
        const int pk_ = kk ? posK1 : posK0; \
        bf16x8 bfr[4]; \
        _Pragma("unroll") \
        for (int nt = 0; nt < 4; ++nt) \
            bfr[nt] = *(const bf16x8*)(Bs_ + nt * 2048 + rowB + pk_); \
        MM16(afc[kk], bfr); \
    } \
} while (0)

// s2: A (Ql) slot {4,0,4,1}[wm+D]; B from bfc
#define STEP_S2(D_) do { \
    const int xa_ = wm + (D_); \
    const char* As_ = smem + ((xa_ & 1) ? (xa_ >> 1) : 4) * 8192; \
    _Pragma("unroll") \
    for (int kk = 0; kk < 2; ++kk) { \
        const int pk_ = kk ? posK1 : posK0; \
        bf16x8 af[4]; \
        _Pragma("unroll") \
        for (int mt = 0; mt < 4; ++mt) \
            af[mt] = *(const bf16x8*)(As_ + mt * 2048 + rowB + pk_); \
        MM16(af, bfc[kk]); \
    } \
} while (0)

__global__ __launch_bounds__(256, 2)
void gemm_fused_kernel(const unsigned short* __restrict__ Aq, const unsigned short* __restrict__ Bq,
                       const float* __restrict__ rnkA,
                       float* __restrict__ part_val, int* __restrict__ part_arg) {
    __shared__ __align__(16) char smem[81920];   // A 5x8K | B 5x8K; epilogue aliases A region
    char* const smemB = smem + 40960;
    const int tid = threadIdx.x;
    const int lane = tid & 63, wid = tid >> 6;
    const int m15 = lane & 15, quad = lane >> 4;
    const int wm = wid & 1, wn = wid >> 1;
    // XCD-chunked swizzle: per-b 1024 wgs; XCD x owns contiguous original
    // range [x*128,(x+1)*128) = 4 q-tiles x all 32 k-tiles (~2MB < 4MB L2).
    const int f = blockIdx.x + (blockIdx.y << 5);
    const int o = ((f & 7) << 7) + (f >> 3);
    const int kt = o & 31, qt = o >> 5;
    const int k0 = kt << 7;
    const int q0 = qt << 7;
    const int b = blockIdx.z;
    const char* Aqb = (const char*)(Aq + (size_t)b * 4096 * 192);
    const char* Bqb = (const char*)(Bq + (size_t)b * 4096 * 192);
    const bool aInt = (q0 >= 64) && (q0 <= 4096 - 192);   // A slab fully in-image
    const bool bInt = (k0 >= 64) && (k0 <= 4096 - 192);

    // per-thread staging offsets (chunk = 64 rows x 8 pos x 16B; pos^=(row&7))
    const int rr0 = tid >> 3, ps = tid & 7;
    const int g0off = rr0 * 384 + (ps ^ (rr0 & 7)) * 16;
    const int l0off = tid * 16;
    const int rr1 = (256 + tid) >> 3;
    const int g1off = rr1 * 384 + (ps ^ (rr1 & 7)) * 16;
    const int l1off = (256 + tid) * 16;
    // per-thread fragment-read offsets
    const int rowB = m15 * 128;
    const int posK0 = (quad ^ (m15 & 7)) * 16;
    const int posK1 = ((4 + quad) ^ (m15 & 7)) * 16;

    floatx4 acc[4][4];
#pragma unroll
    for (int i = 0; i < 4; ++i)
#pragma unroll
        for (int j = 0; j < 4; ++j) acc[i][j] = (floatx4)0.f;

    bf16x8 afc[2][4];   // s0 A-frag cache -> s1 (one dy live)
    bf16x8 bfc[2][4];   // s0 B-frag cache -> s2 (one dy live)

    if (aInt && bInt) {
        // chunk issue ids: c1 Ah0, c2 Ah1, c3 Bh0, c4 Bh1, c5 Ah2, c6 Bh2,
        // c7 Ah3, c8 Bl0, c9 Bl1, c10 Al0 | t1: c11 Al1, c12 Bl2 | t2: c13 Bh3
        // t3: c14 Al2 | t4: c15 Bl3 | t5: c16 Al3.   (2 loads/thread/chunk)
        ISSUE_A(0, 0, 0); ISSUE_A(1, 0, 1); ISSUE_B(0, 0, 0); ISSUE_B(1, 0, 1);
        ISSUE_A(2, 0, 2); ISSUE_B(2, 0, 2); ISSUE_A(3, 0, 3); ISSUE_B(0, 1, 3);
        ISSUE_B(1, 1, 4); ISSUE_A(0, 2, 4);
        PBAR(12);                                      STEP_S0(0);  // needs c1-c4
        PBAR(2);  ISSUE_A(1, 2, 0); ISSUE_B(2, 1, 0); STEP_S1(0);  // needs c8,c9
        PBAR(2);  ISSUE_B(3, 0, 3);                   STEP_S2(0);  // needs c10,c11
        PBAR(14); ISSUE_A(2, 2, 4);                   STEP_S0(1);  // needs c2,c4,c5,c6
        PBAR(4);  ISSUE_B(3, 1, 1);                   STEP_S1(1);  // needs c9,c12
        PBAR(2);  ISSUE_A(3, 2, 1);                   STEP_S2(1);  // needs c11,c14
        PBAR(6);                                      STEP_S0(2);  // needs c5,c6,c7,c13
        PBAR(2);                                      STEP_S1(2);  // needs c12,c15
        PBAR(0);                                      STEP_S2(2);  // needs c14,c16
        __syncthreads();   // slabs dead before epilogue overwrites
    } else {
        // ---- legacy guarded path (boundary blocks): stage full slabs per seg ----
        for (int seg = 0; seg < 3; ++seg) {
            const char* abL = Aqb + (size_t)(q0 - 64) * 384 + seg * 128;
            const char* bbL = Bqb + (size_t)(k0 - 64) * 384 + seg * 128;
            if (aInt) {
#pragma unroll
                for (int it = 0; it < 8; ++it) {
                    int slot = it * 256 + tid;
                    int row = slot >> 3, pos = slot & 7;
                    int G = pos ^ (row & 7);
                    gload_lds16(abL + (size_t)row * 384 + G * 16, smem + slot * 16);
                }
            } else {
#pragma unroll
                for (int it = 0; it < 8; ++it) {
                    int slot = it * 256 + tid;
                    int row = slot >> 3, pos = slot & 7;
                    int G = pos ^ (row & 7);
                    uint4 v = make_uint4(0u, 0u, 0u, 0u);
                    if ((unsigned)(q0 - 64 + row) < 4096u)
                        v = *(const uint4*)(abL + (size_t)row * 384 + G * 16);
                    *(uint4*)(smem + slot * 16) = v;
                }
            }
            if (bInt) {
#pragma unroll
                for (int it = 0; it < 8; ++it) {
                    int slot = it * 256 + tid;
                    int row = slot >> 3, pos = slot & 7;
                    int G = pos ^ (row & 7);
                    gload_lds16(bbL + (size_t)row * 384 + G * 16, smemB + slot * 16);
                }
            } else {
#pragma unroll
                for (int it = 0; it < 8; ++it) {
                    int slot = it * 256 + tid;
                    int row = slot >> 3, pos = slot & 7;
                    int G = pos ^ (row & 7);
                    uint4 v = make_uint4(0u, 0u, 0u, 0u);
                    if ((unsigned)(k0 - 64 + row) < 4096u)
                        v = *(const uint4*)(bbL + (size_t)row * 384 + G * 16);
                    *(uint4*)(smemB + slot * 16) = v;
                }
            }
            __syncthreads();
            STEP_S0(0); STEP_S0(1); STEP_S0(2);
            __syncthreads();
        }
    }

    // ---- epilogue: two 64-row phases; x-3sum + max/argmax over the 128-k tile,
    // then cross-quarter LDS reduce -> one partial per (block, q) ----
    float* Csh = (float*)smem;               // [64][133]
    float* bvs = (float*)(smem + 34816);     // [4][64]
    int*   bas = (int*)(smem + 35840);       // [4][64]
    const int q_l = tid & 63;
    const int qr = tid >> 6;                 // k-quarter (0..3), one per wave
    const int c0 = qr * 32;
    const float4 zero4 = make_float4(0.f, 0.f, 0.f, 0.f);

#pragma unroll
    for (int h = 0; h < 2; ++h) {
        if (h) __syncthreads();              // phase-0 readers done before overwrite
        if (wm == h) {
#pragma unroll
            for (int mt = 0; mt < 4; ++mt)
#pragma unroll
                for (int nt = 0; nt < 4; ++nt)
#pragma unroll
                    for (int j = 0; j < 4; ++j)
                        Csh[(mt * 16 + quad * 4 + j) * 133 + wn * 64 + nt * 16 + m15] =
                            acc[mt][nt][j];
        }
        __syncthreads();

        const bool qm = q_l > 0;             // qx>0: diag- allowed
        const bool qp = q_l < 63;            // qx<63: diag+ allowed
        const float* rC = Csh + q_l * 133;
        const float* rM = Csh + (q_l - 1) * 133;
        const float* rP = Csh + (q_l + 1) * 133;
        float4 prevm = (qm && c0 > 0) ? *(const float4*)&rM[c0 - 4] : zero4;
        float4 rpj   = qp ? *(const float4*)&rP[c0] : zero4;
        float bv = -INFINITY;
        int ba = 0;
#pragma unroll
        for (int j = 0; j < 8; ++j) {
            int c = c0 + 4 * j;
            float4 cen = *(const float4*)&rC[c];
            float4 rm4 = qm ? *(const float4*)&rM[c] : zero4;
            float4 rp1 = (qp && (c + 4) < 128) ? *(const float4*)&rP[c + 4] : zero4;
            float4 o4;
            o4.x = cen.x + (((c & 63) != 0) ? prevm.w : 0.f) + rpj.y;
            o4.y = cen.y + rm4.x + rpj.z;
            o4.z = cen.z + rm4.y + rpj.w;
            o4.w = cen.w + rm4.z + ((((c + 3) & 63) != 63) ? rp1.x : 0.f);
            float4 rk = *(const float4*)&rnkA[(b << 12) + k0 + c];
            // ascending k + strict > = first-occurrence argmax
            float v0 = o4.x * rk.x; if (v0 > bv) { bv = v0; ba = k0 + c + 0; }
            float v1 = o4.y * rk.y; if (v1 > bv) { bv = v1; ba = k0 + c + 1; }
            float v2 = o4.z * rk.z; if (v2 > bv) { bv = v2; ba = k0 + c + 2; }
            float v3 = o4.w * rk.w; if (v3 > bv) { bv = v3; ba = k0 + c + 3; }
            prevm = rm4;
            rpj = rp1;
        }
        bvs[(qr << 6) + q_l] = bv;
        bas[(qr << 6) + q_l] = ba;
        __syncthreads();
        if (tid < 64) {
            float v = bvs[tid];
            int a = bas[tid];
#pragma unroll
            for (int s = 1; s < 4; ++s) {    // ascending quarter = ascending k
                float v2 = bvs[(s << 6) + tid];
                if (v2 > v) { v = v2; a = bas[(s << 6) + tid]; }
            }
            int q = q0 + h * 64 + tid;
            part_val[(((b << 5) + kt) << 12) + q] = v;
            part_arg[(((b << 5) + kt) << 12) + q] = a;
        }
    }
}

// ---------------- gather + fold, fused combine (32 k-slot partials) ----------
// Combines partials for arg rows y-1..y+1, writes S for row y, then
// T[c,y,x] = (1/9) sum_{dy,dx} Vzp[c, a(q)+d], q=(y-dy,x-dx)
__global__ __launch_bounds__(256)
void gatherS_kernel(const float* __restrict__ V,
                    const float* __restrict__ part_val, const int* __restrict__ part_arg,
                    const float* __restrict__ rnqA,
                    float* __restrict__ S_out, float* __restrict__ T_out) {
    __shared__ int sArg[192];
    const int y = blockIdx.x, b = blockIdx.y;
    const int tid = threadIdx.x;
    if (tid < 192) {
        int r = tid >> 6, x = tid & 63;
        int yy = y - 1 + r;
        int a = 0;
        if ((unsigned)yy < 64u) {
            int base = (b << 17) + (yy << 6) + x;   // part[(b*32+s)][q]
            float bv = -INFINITY; int ba = 0;
#pragma unroll 8
            for (int s = 0; s < 32; ++s) {   // ascending s = ascending k: first max wins
                float v = part_val[base + (s << 12)];
                int aa = part_arg[base + (s << 12)];
                if (v > bv) { bv = v; ba = aa; }
            }
            a = ba;
            if (r == 1) {
                int idx = (b << 12) + (yy << 6) + x;
                S_out[idx] = bv * rnqA[idx];
            }
        }
        sArg[tid] = a;
    }
    __syncthreads();

    const int x = tid & 63, cq = tid >> 6;
    int off[9];
#pragma unroll
    for (int t = 0; t < 9; ++t) {
        int dy = t / 3 - 1, dx = t % 3 - 1;
        int qy = y - dy, qx = x - dx;
        int o = -1;
        if ((unsigned)qy < 64u && (unsigned)qx < 64u) {
            int a = sArg[(1 - dy) * 64 + qx];
            int sy = (a >> 6) + dy, sx = (a & 63) + dx;
            if ((unsigned)sy < 64u && (unsigned)sx < 64u) o = (sy << 6) + sx;
        }
        off[t] = o;
    }
    const float* Vb = V + (size_t)b * 64 * HW;
    float* Tb = T_out + (size_t)b * 64 * HW + (y << 6) + x;
    for (int ci = 0; ci < 16; ++ci) {
        int c = cq * 16 + ci;
        const float* Vc = Vb + (size_t)c * HW;
        float acc = 0.f;
#pragma unroll
        for (int t = 0; t < 9; ++t)
            acc += (off[t] >= 0) ? Vc[off[t]] : 0.f;
        Tb[(size_t)c * HW] = acc * (1.f / 9.f);
    }
}

extern "C" void kernel_launch(void* const* d_in, const int* in_sizes, int n_in,
                              void* d_out, int out_size, void* d_ws, size_t ws_size,
                              hipStream_t stream) {
    const float* V = (const float*)d_in[0];
    const float* K = (const float*)d_in[1];
    const float* Q = (const float*)d_in[2];
    float* S_out = (float*)d_out;            // 4*4096
    float* T_out = S_out + 4 * HW;           // 4*64*4096

    char* ws = (char*)d_ws;
    float* pix2q = (float*)(ws + 0);                 // 64 KB
    float* pix2k = (float*)(ws + 65536);
    float* rnq   = (float*)(ws + 131072);
    float* rnk   = (float*)(ws + 196608);
    float* part_val = (float*)(ws + 262144);         // 4*32*4096 f = 2 MB used
    int*   part_arg = (int*)(ws + 8650752);          // 2 MB used
    unsigned short* Aq = (unsigned short*)(ws + 17039360);   // 4*4096*192 bf16 = 6 MiB
    unsigned short* Bq = (unsigned short*)(ws + 23330816);   // 6 MiB

    prep_kernel<<<dim3(64, 4), 256, 0, stream>>>(Q, K, Aq, Bq, pix2q, pix2k);
    patchnorm_kernel<<<64, 256, 0, stream>>>(pix2q, pix2k, rnq, rnk);
    gemm_fused_kernel<<<dim3(32, 32, 4), 256, 0, stream>>>(Aq, Bq, rnk, part_val, part_arg);
    gatherS_kernel<<<dim3(64, 4), 256, 0, stream>>>(V, part_val, part_arg, rnq, S_out, T_out);
}

// Round 4
// 201.885 us; speedup vs baseline: 1.2451x; 1.0141x over previous
//
#include <hip/hip_runtime.h>
#include <math.h>

#define HW 4096   // H*W = 64*64; B=4, C=64, H=W=64, L=4096

typedef short bf16x8 __attribute__((ext_vector_type(8)));
typedef float floatx4 __attribute__((ext_vector_type(4)));
typedef unsigned short u16x8 __attribute__((ext_vector_type(8)));

__device__ __forceinline__ unsigned short f2bf_rne(float x) {
    unsigned int u = __float_as_uint(x);
    unsigned int r = (u + 0x7FFFu + ((u >> 16) & 1u)) >> 16;
    return (unsigned short)r;
}
__device__ __forceinline__ float bf2f(unsigned short h) {
    return __uint_as_float(((unsigned int)h) << 16);
}

// async global->LDS, 16 B per lane; LDS dest is wave-uniform base + lane*16.
__device__ __forceinline__ void gload_lds16(const void* gptr, void* lptr) {
    auto g = (const __attribute__((address_space(1))) unsigned int*)(unsigned long long)(gptr);
    auto l = (__attribute__((address_space(3))) unsigned int*)(unsigned int)(unsigned long long)(lptr);
    __builtin_amdgcn_global_load_lds(g, l, 16, 0, 0);
}

// ---------------- prep: split fp32 -> bf16 (hi,lo), transpose to [p][c], ------
// fused per-pixel squared norms. Aq[b][p] = [Qh|Qh|Ql], Bq[b][p] = [Kh|Kl|Kh]
// so a 192-dot gives QhKh + QhKl + QlKh ~= fp32 dot.  blockIdx.z picks Q or K
// (2x blocks -> 2 blocks/CU for latency hiding).  16B vector stores.
__global__ __launch_bounds__(256)
void prep_kernel(const float* __restrict__ Q, const float* __restrict__ K,
                 unsigned short* __restrict__ Aq, unsigned short* __restrict__ Bq,
                 float* __restrict__ pix2q, float* __restrict__ pix2k) {
    __shared__ float sT[64][65];
    const int tid = threadIdx.x;
    const int p0 = blockIdx.x * 64;
    const int b = blockIdx.y;
    const int isK = blockIdx.z;
    const float* __restrict__ src = isK ? K : Q;
    unsigned short* __restrict__ dst = isK ? Bq : Aq;
    float* __restrict__ pix2 = isK ? pix2k : pix2q;
    const int pp = tid >> 2, qt = tid & 3;
    const size_t base = ((size_t)b * 4096 + p0 + pp) * 192;

#pragma unroll
    for (int it = 0; it < 16; ++it) {
        int idx = it * 256 + tid;
        int c = idx >> 6, x = idx & 63;
        sT[c][x] = src[((size_t)b * 64 + c) * HW + p0 + x];
    }
    __syncthreads();
    {
        float sq = 0.f;
        u16x8 hv[2], lv[2];
#pragma unroll
        for (int g = 0; g < 2; ++g)
#pragma unroll
            for (int j = 0; j < 8; ++j) {
                int c = qt * 16 + g * 8 + j;
                float x = sT[c][pp];
                sq = fmaf(x, x, sq);
                unsigned short h = f2bf_rne(x);
                hv[g][j] = h;
                lv[g][j] = f2bf_rne(x - bf2f(h));
            }
        sq += __shfl_xor(sq, 1, 64);
        sq += __shfl_xor(sq, 2, 64);
        if (qt == 0) pix2[(b << 12) + p0 + pp] = sq;
#pragma unroll
        for (int g = 0; g < 2; ++g) {
            int co = qt * 16 + g * 8;
            *(u16x8*)(dst + base + co)       = hv[g];             // slice0: h
            *(u16x8*)(dst + base + 64 + co)  = isK ? lv[g] : hv[g]; // slice1
            *(u16x8*)(dst + base + 128 + co) = isK ? hv[g] : lv[g]; // slice2
        }
    }
}

// ---------------- patch reciprocal norms: 1/max(sqrt(3x3 box sum), 1e-12) ----
__global__ void patchnorm_kernel(const float* __restrict__ pix2q, const float* __restrict__ pix2k,
                                 float* __restrict__ rnq, float* __restrict__ rnk) {
    int idx = blockIdx.x * 256 + threadIdx.x;   // b*4096 + p
    int b = idx >> 12, p = idx & 4095;
    int py = p >> 6, px = p & 63;
    float sq = 0.f, sk = 0.f;
    for (int dy = -1; dy <= 1; ++dy)
        for (int dx = -1; dx <= 1; ++dx) {
            int yy = py + dy, xx = px + dx;
            if ((unsigned)yy < 64u && (unsigned)xx < 64u) {
                int o = (b << 12) + (yy << 6) + xx;
                sq += pix2q[o];
                sk += pix2k[o];
            }
        }
    rnq[idx] = 1.f / fmaxf(sqrtf(sq), 1e-12f);
    rnk[idx] = 1.f / fmaxf(sqrtf(sk), 1e-12f);
}

// ---------------- fused MFMA GEMM (K=576: y-3sum in K) + x-3sum + argmax -----
// Slice identities: Aq=[Qh|Qh|Ql] (slice1==slice0), Bq=[Kh|Kl|Kh]
// (slice2==slice0). Step order (s0,s1,s2) per dy:
//   s0 = Qh.Kh : A,B from LDS; cache A frags->afc, B frags->bfc (1 dy live)
//   s1 = Qh.Kl : A = afc (no LDS), B = Bl from LDS
//   s2 = Ql.Kh : A = Al from LDS, B = bfc (no LDS, and Bh' NEVER STAGED)
// 16 staged chunks, 96 ds_read_b128/wave.  LDS: A 5 | B 5 slots = 80 KB.
#define WAITV(n_) asm volatile("s_waitcnt vmcnt(" #n_ ")" ::: "memory")
#define PBAR(n_) do { WAITV(n_); __builtin_amdgcn_s_barrier(); \
                      asm volatile("" ::: "memory"); } while (0)

#define ISSUE_A(c_, sg_, slot_) do { \
    const char* g_ = Aqb + (size_t)(q0 - 64 + (c_) * 64) * 384 + (sg_) * 128; \
    gload_lds16(g_ + g0off, smem + (slot_) * 8192 + l0off); \
    gload_lds16(g_ + g1off, smem + (slot_) * 8192 + l1off); \
} while (0)
#define ISSUE_B(c_, sg_, slot_) do { \
    const char* g_ = Bqb + (size_t)(k0 - 64 + (c_) * 64) * 384 + (sg_) * 128; \
    gload_lds16(g_ + g0off, smemB + (slot_) * 8192 + l0off); \
    gload_lds16(g_ + g1off, smemB + (slot_) * 8192 + l1off); \
} while (0)

#define MM16(af_, bfr_) do { \
    __builtin_amdgcn_s_setprio(1); \
    _Pragma("unroll") \
    for (int mt = 0; mt < 4; ++mt) \
        _Pragma("unroll") \
        for (int nt = 0; nt < 4; ++nt) \
            acc[mt][nt] = __builtin_amdgcn_mfma_f32_16x16x32_bf16( \
                (af_)[mt], (bfr_)[nt], acc[mt][nt], 0, 0, 0); \
    __builtin_amdgcn_s_setprio(0); \
} while (0)

// s0: A slot (wm+D), B slot (wn+D); cache both fragment sets
#define STEP_S0(D_) do { \
    const char* As_ = smem + (wm + (D_)) * 8192; \
    const char* Bs_ = smemB + (wn + (D_)) * 8192; \
    _Pragma("unroll") \
    for (int kk = 0; kk < 2; ++kk) { \
        const int pk_ = kk ? posK1 : posK0; \
        _Pragma("unroll") \
        for (int mt = 0; mt < 4; ++mt) \
            afc[kk][mt] = *(const bf16x8*)(As_ + mt * 2048 + rowB + pk_); \
        _Pragma("unroll") \
        for (int nt = 0; nt < 4; ++nt) \
            bfc[kk][nt] = *(const bf16x8*)(Bs_ + nt * 2048 + rowB + pk_); \
        MM16(afc[kk], bfc[kk]); \
    } \
} while (0)

// s1: A from afc; B (Kl) slot {3,4,0,1}[wn+D]
#define STEP_S1(D_) do { \
    const int xb_ = wn + (D_); \
    const char* Bs_ = smemB + (xb_ < 2 ? xb_ + 3 : xb_ - 2) * 8192; \
    _Pragma("unroll") \
    for (int kk = 0; kk < 2; ++kk) { \
        const int pk_ = kk ? posK1 : posK0; \
        bf16x8 bfr[4]; \
        _Pragma("unroll") \
        for (int nt = 0; nt < 4; ++nt) \
            bfr[nt] = *(const bf16x8*)(Bs_ + nt * 2048 + rowB + pk_); \
        MM16(afc[kk], bfr); \
    } \
} while (0)

// s2: A (Ql) slot {4,0,4,1}[wm+D]; B from bfc
#define STEP_S2(D_) do { \
    const int xa_ = wm + (D_); \
    const char* As_ = smem + ((xa_ & 1) ? (xa_ >> 1) : 4) * 8192; \
    _Pragma("unroll") \
    for (int kk = 0; kk < 2; ++kk) { \
        const int pk_ = kk ? posK1 : posK0; \
        bf16x8 af[4]; \
        _Pragma("unroll") \
        for (int mt = 0; mt < 4; ++mt) \
            af[mt] = *(const bf16x8*)(As_ + mt * 2048 + rowB + pk_); \
        MM16(af, bfc[kk]); \
    } \
} while (0)

__global__ __launch_bounds__(256, 2)
void gemm_fused_kernel(const unsigned short* __restrict__ Aq, const unsigned short* __restrict__ Bq,
                       const float* __restrict__ rnkA,
                       float* __restrict__ part_val, int* __restrict__ part_arg) {
    __shared__ __align__(16) char smem[81920];   // A 5x8K | B 5x8K; epilogue aliases A region
    char* const smemB = smem + 40960;
    const int tid = threadIdx.x;
    const int lane = tid & 63, wid = tid >> 6;
    const int m15 = lane & 15, quad = lane >> 4;
    const int wm = wid & 1, wn = wid >> 1;
    // XCD-chunked swizzle: per-b 1024 wgs; XCD x owns contiguous original
    // range [x*128,(x+1)*128) = 4 q-tiles x all 32 k-tiles (~2MB < 4MB L2).
    const int f = blockIdx.x + (blockIdx.y << 5);
    const int o = ((f & 7) << 7) + (f >> 3);
    const int kt = o & 31, qt = o >> 5;
    const int k0 = kt << 7;
    const int q0 = qt << 7;
    const int b = blockIdx.z;
    const char* Aqb = (const char*)(Aq + (size_t)b * 4096 * 192);
    const char* Bqb = (const char*)(Bq + (size_t)b * 4096 * 192);
    const bool aInt = (q0 >= 64) && (q0 <= 4096 - 192);   // A slab fully in-image
    const bool bInt = (k0 >= 64) && (k0 <= 4096 - 192);

    // per-thread staging offsets (chunk = 64 rows x 8 pos x 16B; pos^=(row&7))
    const int rr0 = tid >> 3, ps = tid & 7;
    const int g0off = rr0 * 384 + (ps ^ (rr0 & 7)) * 16;
    const int l0off = tid * 16;
    const int rr1 = (256 + tid) >> 3;
    const int g1off = rr1 * 384 + (ps ^ (rr1 & 7)) * 16;
    const int l1off = (256 + tid) * 16;
    // per-thread fragment-read offsets
    const int rowB = m15 * 128;
    const int posK0 = (quad ^ (m15 & 7)) * 16;
    const int posK1 = ((4 + quad) ^ (m15 & 7)) * 16;

    floatx4 acc[4][4];
#pragma unroll
    for (int i = 0; i < 4; ++i)
#pragma unroll
        for (int j = 0; j < 4; ++j) acc[i][j] = (floatx4)0.f;

    bf16x8 afc[2][4];   // s0 A-frag cache -> s1 (one dy live)
    bf16x8 bfc[2][4];   // s0 B-frag cache -> s2 (one dy live)

    if (aInt && bInt) {
        // chunk issue ids: c1 Ah0, c2 Ah1, c3 Bh0, c4 Bh1, c5 Ah2, c6 Bh2,
        // c7 Ah3, c8 Bl0, c9 Bl1, c10 Al0 | t1: c11 Al1, c12 Bl2 | t2: c13 Bh3
        // t3: c14 Al2 | t4: c15 Bl3 | t5: c16 Al3.   (2 loads/thread/chunk)
        ISSUE_A(0, 0, 0); ISSUE_A(1, 0, 1); ISSUE_B(0, 0, 0); ISSUE_B(1, 0, 1);
        ISSUE_A(2, 0, 2); ISSUE_B(2, 0, 2); ISSUE_A(3, 0, 3); ISSUE_B(0, 1, 3);
        ISSUE_B(1, 1, 4); ISSUE_A(0, 2, 4);
        PBAR(12);                                      STEP_S0(0);  // needs c1-c4
        PBAR(2);  ISSUE_A(1, 2, 0); ISSUE_B(2, 1, 0); STEP_S1(0);  // needs c8,c9
        PBAR(2);  ISSUE_B(3, 0, 3);                   STEP_S2(0);  // needs c10,c11
        PBAR(14); ISSUE_A(2, 2, 4);                   STEP_S0(1);  // needs c2,c4,c5,c6
        PBAR(4);  ISSUE_B(3, 1, 1);                   STEP_S1(1);  // needs c9,c12
        PBAR(2);  ISSUE_A(3, 2, 1);                   STEP_S2(1);  // needs c11,c14
        PBAR(6);                                      STEP_S0(2);  // needs c5,c6,c7,c13
        PBAR(2);                                      STEP_S1(2);  // needs c12,c15
        PBAR(0);                                      STEP_S2(2);  // needs c14,c16
        __syncthreads();   // slabs dead before epilogue overwrites
    } else {
        // ---- legacy guarded path (boundary blocks): stage full slabs per seg ----
        for (int seg = 0; seg < 3; ++seg) {
            const char* abL = Aqb + (size_t)(q0 - 64) * 384 + seg * 128;
            const char* bbL = Bqb + (size_t)(k0 - 64) * 384 + seg * 128;
            if (aInt) {
#pragma unroll
                for (int it = 0; it < 8; ++it) {
                    int slot = it * 256 + tid;
                    int row = slot >> 3, pos = slot & 7;
                    int G = pos ^ (row & 7);
                    gload_lds16(abL + (size_t)row * 384 + G * 16, smem + slot * 16);
                }
            } else {
#pragma unroll
                for (int it = 0; it < 8; ++it) {
                    int slot = it * 256 + tid;
                    int row = slot >> 3, pos = slot & 7;
                    int G = pos ^ (row & 7);
                    uint4 v = make_uint4(0u, 0u, 0u, 0u);
                    if ((unsigned)(q0 - 64 + row) < 4096u)
                        v = *(const uint4*)(abL + (size_t)row * 384 + G * 16);
                    *(uint4*)(smem + slot * 16) = v;
                }
            }
            if (bInt) {
#pragma unroll
                for (int it = 0; it < 8; ++it) {
                    int slot = it * 256 + tid;
                    int row = slot >> 3, pos = slot & 7;
                    int G = pos ^ (row & 7);
                    gload_lds16(bbL + (size_t)row * 384 + G * 16, smemB + slot * 16);
                }
            } else {
#pragma unroll
                for (int it = 0; it < 8; ++it) {
                    int slot = it * 256 + tid;
                    int row = slot >> 3, pos = slot & 7;
                    int G = pos ^ (row & 7);
                    uint4 v = make_uint4(0u, 0u, 0u, 0u);
                    if ((unsigned)(k0 - 64 + row) < 4096u)
                        v = *(const uint4*)(bbL + (size_t)row * 384 + G * 16);
                    *(uint4*)(smemB + slot * 16) = v;
                }
            }
            __syncthreads();
            STEP_S0(0); STEP_S0(1); STEP_S0(2);
            __syncthreads();
        }
    }

    // ---- epilogue: two 64-row phases; x-3sum + max/argmax over the 128-k tile,
    // then cross-quarter LDS reduce -> one partial per (block, q) ----
    float* Csh = (float*)smem;               // [64][133]
    float* bvs = (float*)(smem + 34816);     // [4][64]
    int*   bas = (int*)(smem + 35840);       // [4][64]
    const int q_l = tid & 63;
    const int qr = tid >> 6;                 // k-quarter (0..3), one per wave
    const int c0 = qr * 32;
    const float4 zero4 = make_float4(0.f, 0.f, 0.f, 0.f);

#pragma unroll
    for (int h = 0; h < 2; ++h) {
        if (h) __syncthreads();              // phase-0 readers done before overwrite
        if (wm == h) {
#pragma unroll
            for (int mt = 0; mt < 4; ++mt)
#pragma unroll
                for (int nt = 0; nt < 4; ++nt)
#pragma unroll
                    for (int j = 0; j < 4; ++j)
                        Csh[(mt * 16 + quad * 4 + j) * 133 + wn * 64 + nt * 16 + m15] =
                            acc[mt][nt][j];
        }
        __syncthreads();

        const bool qm = q_l > 0;             // qx>0: diag- allowed
        const bool qp = q_l < 63;            // qx<63: diag+ allowed
        const float* rC = Csh + q_l * 133;
        const float* rM = Csh + (q_l - 1) * 133;
        const float* rP = Csh + (q_l + 1) * 133;
        float4 prevm = (qm && c0 > 0) ? *(const float4*)&rM[c0 - 4] : zero4;
        float4 rpj   = qp ? *(const float4*)&rP[c0] : zero4;
        float bv = -INFINITY;
        int ba = 0;
#pragma unroll
        for (int j = 0; j < 8; ++j) {
            int c = c0 + 4 * j;
            float4 cen = *(const float4*)&rC[c];
            float4 rm4 = qm ? *(const float4*)&rM[c] : zero4;
            float4 rp1 = (qp && (c + 4) < 128) ? *(const float4*)&rP[c + 4] : zero4;
            float4 o4;
            o4.x = cen.x + (((c & 63) != 0) ? prevm.w : 0.f) + rpj.y;
            o4.y = cen.y + rm4.x + rpj.z;
            o4.z = cen.z + rm4.y + rpj.w;
            o4.w = cen.w + rm4.z + ((((c + 3) & 63) != 63) ? rp1.x : 0.f);
            float4 rk = *(const float4*)&rnkA[(b << 12) + k0 + c];
            // ascending k + strict > = first-occurrence argmax
            float v0 = o4.x * rk.x; if (v0 > bv) { bv = v0; ba = k0 + c + 0; }
            float v1 = o4.y * rk.y; if (v1 > bv) { bv = v1; ba = k0 + c + 1; }
            float v2 = o4.z * rk.z; if (v2 > bv) { bv = v2; ba = k0 + c + 2; }
            float v3 = o4.w * rk.w; if (v3 > bv) { bv = v3; ba = k0 + c + 3; }
            prevm = rm4;
            rpj = rp1;
        }
        bvs[(qr << 6) + q_l] = bv;
        bas[(qr << 6) + q_l] = ba;
        __syncthreads();
        if (tid < 64) {
            float v = bvs[tid];
            int a = bas[tid];
#pragma unroll
            for (int s = 1; s < 4; ++s) {    // ascending quarter = ascending k
                float v2 = bvs[(s << 6) + tid];
                if (v2 > v) { v = v2; a = bas[(s << 6) + tid]; }
            }
            int q = q0 + h * 64 + tid;
            part_val[(((b << 5) + kt) << 12) + q] = v;
            part_arg[(((b << 5) + kt) << 12) + q] = a;
        }
    }
}

// ---------------- combine 32 k-slot partials -> final arg + S ----------------
__global__ __launch_bounds__(256)
void argcombine_kernel(const float* __restrict__ part_val, const int* __restrict__ part_arg,
                       const float* __restrict__ rnqA,
                       float* __restrict__ S_out, int* __restrict__ argF) {
    __shared__ float rv[4][64];
    __shared__ int ra[4][64];
    const int tid = threadIdx.x;
    const int qi = tid & 63, sg = tid >> 6;
    const int q = blockIdx.x * 64 + qi;
    const int b = blockIdx.y;
    const int base = (b << 17) + q;
    float bv = -INFINITY; int ba = 0;
#pragma unroll
    for (int s8 = 0; s8 < 8; ++s8) {         // ascending s = ascending k
        int s = sg * 8 + s8;
        float v = part_val[base + (s << 12)];
        int aa = part_arg[base + (s << 12)];
        if (v > bv) { bv = v; ba = aa; }
    }
    rv[sg][qi] = bv; ra[sg][qi] = ba;
    __syncthreads();
    if (tid < 64) {
        float v = rv[0][tid]; int a = ra[0][tid];
#pragma unroll
        for (int s = 1; s < 4; ++s) {        // ascending group: first max wins
            float v2 = rv[s][tid];
            if (v2 > v) { v = v2; a = ra[s][tid]; }
        }
        int idx = (b << 12) + blockIdx.x * 64 + tid;
        S_out[idx] = v * rnqA[idx];
        argF[idx] = a;
    }
}

// ---------------- gather + fold: T[c,y,x] = (1/9) sum_9 Vzp[c, a(q)+d] -------
// Channels split over blockIdx.z: 1024 blocks = 4 blocks/CU so the scattered
// V gather has TLP to hide latency (old fused kernel ran 1 block/CU).
__global__ __launch_bounds__(256)
void gatherT_kernel(const float* __restrict__ V, const int* __restrict__ argF,
                    float* __restrict__ T_out) {
    __shared__ int sArg[192];
    const int y = blockIdx.x, b = blockIdx.y, cg = blockIdx.z;
    const int tid = threadIdx.x;
    if (tid < 192) {
        int r = tid >> 6, x = tid & 63;
        int yy = y - 1 + r;
        sArg[tid] = ((unsigned)yy < 64u) ? argF[(b << 12) + (yy << 6) + x] : 0;
    }
    __syncthreads();

    const int x = tid & 63, cq = tid >> 6;
    int off[9];
#pragma unroll
    for (int t = 0; t < 9; ++t) {
        int dy = t / 3 - 1, dx = t % 3 - 1;
        int qy = y - dy, qx = x - dx;
        int o = -1;
        if ((unsigned)qy < 64u && (unsigned)qx < 64u) {
            int a = sArg[(1 - dy) * 64 + qx];
            int sy = (a >> 6) + dy, sx = (a & 63) + dx;
            if ((unsigned)sy < 64u && (unsigned)sx < 64u) o = (sy << 6) + sx;
        }
        off[t] = o;
    }
    const float* Vb = V + (size_t)b * 64 * HW;
    float* Tb = T_out + (size_t)b * 64 * HW + (y << 6) + x;
#pragma unroll
    for (int ci = 0; ci < 4; ++ci) {
        int c = cg * 16 + cq * 4 + ci;
        const float* Vc = Vb + (size_t)c * HW;
        float acc = 0.f;
#pragma unroll
        for (int t = 0; t < 9; ++t)
            acc += (off[t] >= 0) ? Vc[off[t]] : 0.f;
        Tb[(size_t)c * HW] = acc * (1.f / 9.f);
    }
}

extern "C" void kernel_launch(void* const* d_in, const int* in_sizes, int n_in,
                              void* d_out, int out_size, void* d_ws, size_t ws_size,
                              hipStream_t stream) {
    const float* V = (const float*)d_in[0];
    const float* K = (const float*)d_in[1];
    const float* Q = (const float*)d_in[2];
    float* S_out = (float*)d_out;            // 4*4096
    float* T_out = S_out + 4 * HW;           // 4*64*4096

    char* ws = (char*)d_ws;
    float* pix2q = (float*)(ws + 0);                 // 64 KB
    float* pix2k = (float*)(ws + 65536);
    float* rnq   = (float*)(ws + 131072);
    float* rnk   = (float*)(ws + 196608);
    float* part_val = (float*)(ws + 262144);         // 4*32*4096 f = 2 MB used
    int*   argF  = (int*)(ws + 4456448);             // 64 KB (within part_val slot)
    int*   part_arg = (int*)(ws + 8650752);          // 2 MB used
    unsigned short* Aq = (unsigned short*)(ws + 17039360);   // 4*4096*192 bf16 = 6 MiB
    unsigned short* Bq = (unsigned short*)(ws + 23330816);   // 6 MiB

    prep_kernel<<<dim3(64, 4, 2), 256, 0, stream>>>(Q, K, Aq, Bq, pix2q, pix2k);
    patchnorm_kernel<<<64, 256, 0, stream>>>(pix2q, pix2k, rnq, rnk);
    gemm_fused_kernel<<<dim3(32, 32, 4), 256, 0, stream>>>(Aq, Bq, rnk, part_val, part_arg);
    argcombine_kernel<<<dim3(64, 4), 256, 0, stream>>>(part_val, part_arg, rnq, S_out, argF);
    gatherT_kernel<<<dim3(64, 4, 4), 256, 0, stream>>>(V, argF, T_out);
}

// Round 5
// 191.782 us; speedup vs baseline: 1.3107x; 1.0527x over previous
//
#include <hip/hip_runtime.h>
#include <math.h>

#define HW 4096   // H*W = 64*64; B=4, C=64, H=W=64, L=4096

typedef short bf16x8 __attribute__((ext_vector_type(8)));
typedef float floatx4 __attribute__((ext_vector_type(4)));
typedef unsigned short u16x8 __attribute__((ext_vector_type(8)));

__device__ __forceinline__ unsigned short f2bf_rne(float x) {
    unsigned int u = __float_as_uint(x);
    unsigned int r = (u + 0x7FFFu + ((u >> 16) & 1u)) >> 16;
    return (unsigned short)r;
}
__device__ __forceinline__ float bf2f(unsigned short h) {
    return __uint_as_float(((unsigned int)h) << 16);
}

// async global->LDS, 16 B per lane; LDS dest is wave-uniform base + lane*16.
__device__ __forceinline__ void gload_lds16(const void* gptr, void* lptr) {
    auto g = (const __attribute__((address_space(1))) unsigned int*)(unsigned long long)(gptr);
    auto l = (__attribute__((address_space(3))) unsigned int*)(unsigned int)(unsigned long long)(lptr);
    __builtin_amdgcn_global_load_lds(g, l, 16, 0, 0);
}

// ---------------- prep: z=0 Q / z=1 K: split fp32 -> bf16 (hi,lo), transpose
// to [p][c], fused per-pixel squared norms. Aq[b][p]=[Qh|Qh|Ql],
// Bq[b][p]=[Kh|Kl|Kh] so a 192-dot gives QhKh+QhKl+QlKh ~= fp32 dot.
// z=2: transpose V -> VT[b][p][c] (f32) so gatherT reads channels contiguous.
__global__ __launch_bounds__(256)
void prep_kernel(const float* __restrict__ Q, const float* __restrict__ K,
                 const float* __restrict__ V,
                 unsigned short* __restrict__ Aq, unsigned short* __restrict__ Bq,
                 float* __restrict__ VT,
                 float* __restrict__ pix2q, float* __restrict__ pix2k) {
    __shared__ float sT[64][65];
    const int tid = threadIdx.x;
    const int p0 = blockIdx.x * 64;
    const int b = blockIdx.y;
    const int which = blockIdx.z;            // 0=Q, 1=K, 2=V
    const float* __restrict__ src = (which == 0) ? Q : ((which == 1) ? K : V);

#pragma unroll
    for (int it = 0; it < 16; ++it) {
        int idx = it * 256 + tid;
        int c = idx >> 6, x = idx & 63;
        sT[c][x] = src[((size_t)b * 64 + c) * HW + p0 + x];
    }
    __syncthreads();
    const int pp = tid >> 2, qt = tid & 3;

    if (which == 2) {                        // V: pure f32 transpose
        float* dst = VT + ((size_t)b * 4096 + p0 + pp) * 64 + qt * 16;
#pragma unroll
        for (int j = 0; j < 4; ++j) {
            float4 v = make_float4(sT[qt * 16 + 4 * j + 0][pp], sT[qt * 16 + 4 * j + 1][pp],
                                   sT[qt * 16 + 4 * j + 2][pp], sT[qt * 16 + 4 * j + 3][pp]);
            *(float4*)(dst + 4 * j) = v;
        }
        return;
    }

    const int isK = which;
    unsigned short* __restrict__ dst = isK ? Bq : Aq;
    float* __restrict__ pix2 = isK ? pix2k : pix2q;
    const size_t base = ((size_t)b * 4096 + p0 + pp) * 192;
    {
        float sq = 0.f;
        u16x8 hv[2], lv[2];
#pragma unroll
        for (int g = 0; g < 2; ++g)
#pragma unroll
            for (int j = 0; j < 8; ++j) {
                int c = qt * 16 + g * 8 + j;
                float x = sT[c][pp];
                sq = fmaf(x, x, sq);
                unsigned short h = f2bf_rne(x);
                hv[g][j] = h;
                lv[g][j] = f2bf_rne(x - bf2f(h));
            }
        sq += __shfl_xor(sq, 1, 64);
        sq += __shfl_xor(sq, 2, 64);
        if (qt == 0) pix2[(b << 12) + p0 + pp] = sq;
#pragma unroll
        for (int g = 0; g < 2; ++g) {
            int co = qt * 16 + g * 8;
            *(u16x8*)(dst + base + co)       = hv[g];               // slice0: h
            *(u16x8*)(dst + base + 64 + co)  = isK ? lv[g] : hv[g]; // slice1
            *(u16x8*)(dst + base + 128 + co) = isK ? hv[g] : lv[g]; // slice2
        }
    }
}

// ---------------- patch reciprocal norms: 1/max(sqrt(3x3 box sum), 1e-12) ----
__global__ void patchnorm_kernel(const float* __restrict__ pix2q, const float* __restrict__ pix2k,
                                 float* __restrict__ rnq, float* __restrict__ rnk) {
    int idx = blockIdx.x * 256 + threadIdx.x;   // b*4096 + p
    int b = idx >> 12, p = idx & 4095;
    int py = p >> 6, px = p & 63;
    float sq = 0.f, sk = 0.f;
    for (int dy = -1; dy <= 1; ++dy)
        for (int dx = -1; dx <= 1; ++dx) {
            int yy = py + dy, xx = px + dx;
            if ((unsigned)yy < 64u && (unsigned)xx < 64u) {
                int o = (b << 12) + (yy << 6) + xx;
                sq += pix2q[o];
                sk += pix2k[o];
            }
        }
    rnq[idx] = 1.f / fmaxf(sqrtf(sq), 1e-12f);
    rnk[idx] = 1.f / fmaxf(sqrtf(sk), 1e-12f);
}

// ---------------- fused MFMA GEMM (K=576: y-3sum in K) + x-3sum + argmax -----
// Slice identities: Aq=[Qh|Qh|Ql] (slice1==slice0), Bq=[Kh|Kl|Kh]
// (slice2==slice0). Step order (s0,s1,s2) per dy:
//   s0 = Qh.Kh : A,B from LDS; cache A frags->afc, B frags->bfc (1 dy live)
//   s1 = Qh.Kl : A = afc (no LDS), B = Bl from LDS
//   s2 = Ql.Kh : A = Al from LDS, B = bfc (no LDS, and Bh' NEVER STAGED)
// 16 staged chunks, 96 ds_read_b128/wave.  LDS: A 5 | B 5 slots = 80 KB.
#define WAITV(n_) asm volatile("s_waitcnt vmcnt(" #n_ ")" ::: "memory")
#define PBAR(n_) do { WAITV(n_); __builtin_amdgcn_s_barrier(); \
                      asm volatile("" ::: "memory"); } while (0)

#define ISSUE_A(c_, sg_, slot_) do { \
    const char* g_ = Aqb + (size_t)(q0 - 64 + (c_) * 64) * 384 + (sg_) * 128; \
    gload_lds16(g_ + g0off, smem + (slot_) * 8192 + l0off); \
    gload_lds16(g_ + g1off, smem + (slot_) * 8192 + l1off); \
} while (0)
#define ISSUE_B(c_, sg_, slot_) do { \
    const char* g_ = Bqb + (size_t)(k0 - 64 + (c_) * 64) * 384 + (sg_) * 128; \
    gload_lds16(g_ + g0off, smemB + (slot_) * 8192 + l0off); \
    gload_lds16(g_ + g1off, smemB + (slot_) * 8192 + l1off); \
} while (0)

#define MM16(af_, bfr_) do { \
    __builtin_amdgcn_s_setprio(1); \
    _Pragma("unroll") \
    for (int mt = 0; mt < 4; ++mt) \
        _Pragma("unroll") \
        for (int nt = 0; nt < 4; ++nt) \
            acc[mt][nt] = __builtin_amdgcn_mfma_f32_16x16x32_bf16( \
                (af_)[mt], (bfr_)[nt], acc[mt][nt], 0, 0, 0); \
    __builtin_amdgcn_s_setprio(0); \
} while (0)

// s0: A slot (wm+D), B slot (wn+D); cache both fragment sets
#define STEP_S0(D_) do { \
    const char* As_ = smem + (wm + (D_)) * 8192; \
    const char* Bs_ = smemB + (wn + (D_)) * 8192; \
    _Pragma("unroll") \
    for (int kk = 0; kk < 2; ++kk) { \
        const int pk_ = kk ? posK1 : posK0; \
        _Pragma("unroll") \
        for (int mt = 0; mt < 4; ++mt) \
            afc[kk][mt] = *(const bf16x8*)(As_ + mt * 2048 + rowB + pk_); \
        _Pragma("unroll") \
        for (int nt = 0; nt < 4; ++nt) \
            bfc[kk][nt] = *(const bf16x8*)(Bs_ + nt * 2048 + rowB + pk_); \
        MM16(afc[kk], bfc[kk]); \
    } \
} while (0)

// s1: A from afc; B (Kl) slot {3,4,0,1}[wn+D]
#define STEP_S1(D_) do { \
    const int xb_ = wn + (D_); \
    const char* Bs_ = smemB + (xb_ < 2 ? xb_ + 3 : xb_ - 2) * 8192; \
    _Pragma("unroll") \
    for (int kk = 0; kk < 2; ++kk) { \
        const int pk_ = kk ? posK1 : posK0; \
        bf16x8 bfr[4]; \
        _Pragma("unroll") \
        for (int nt = 0; nt < 4; ++nt) \
            bfr[nt] = *(const bf16x8*)(Bs_ + nt * 2048 + rowB + pk_); \
        MM16(afc[kk], bfr); \
    } \
} while (0)

// s2: A (Ql) slot {4,0,4,1}[wm+D]; B from bfc
#define STEP_S2(D_) do { \
    const int xa_ = wm + (D_); \
    const char* As_ = smem + ((xa_ & 1) ? (xa_ >> 1) : 4) * 8192; \
    _Pragma("unroll") \
    for (int kk = 0; kk < 2; ++kk) { \
        const int pk_ = kk ? posK1 : posK0; \
        bf16x8 af[4]; \
        _Pragma("unroll") \
        for (int mt = 0; mt < 4; ++mt) \
            af[mt] = *(const bf16x8*)(As_ + mt * 2048 + rowB + pk_); \
        MM16(af, bfc[kk]); \
    } \
} while (0)

__global__ __launch_bounds__(256, 2)
void gemm_fused_kernel(const unsigned short* __restrict__ Aq, const unsigned short* __restrict__ Bq,
                       const float* __restrict__ rnkA,
                       float* __restrict__ part_val, int* __restrict__ part_arg) {
    __shared__ __align__(16) char smem[81920];   // A 5x8K | B 5x8K; epilogue aliases A region
    char* const smemB = smem + 40960;
    const int tid = threadIdx.x;
    const int lane = tid & 63, wid = tid >> 6;
    const int m15 = lane & 15, quad = lane >> 4;
    const int wm = wid & 1, wn = wid >> 1;
    // XCD-chunked swizzle: per-b 1024 wgs; XCD x owns contiguous original
    // range [x*128,(x+1)*128) = 4 q-tiles x all 32 k-tiles (~2MB < 4MB L2).
    const int f = blockIdx.x + (blockIdx.y << 5);
    const int o = ((f & 7) << 7) + (f >> 3);
    const int kt = o & 31, qt = o >> 5;
    const int k0 = kt << 7;
    const int q0 = qt << 7;
    const int b = blockIdx.z;
    const char* Aqb = (const char*)(Aq + (size_t)b * 4096 * 192);
    const char* Bqb = (const char*)(Bq + (size_t)b * 4096 * 192);
    const bool aInt = (q0 >= 64) && (q0 <= 4096 - 192);   // A slab fully in-image
    const bool bInt = (k0 >= 64) && (k0 <= 4096 - 192);

    // per-thread staging offsets (chunk = 64 rows x 8 pos x 16B; pos^=(row&7))
    const int rr0 = tid >> 3, ps = tid & 7;
    const int g0off = rr0 * 384 + (ps ^ (rr0 & 7)) * 16;
    const int l0off = tid * 16;
    const int rr1 = (256 + tid) >> 3;
    const int g1off = rr1 * 384 + (ps ^ (rr1 & 7)) * 16;
    const int l1off = (256 + tid) * 16;
    // per-thread fragment-read offsets
    const int rowB = m15 * 128;
    const int posK0 = (quad ^ (m15 & 7)) * 16;
    const int posK1 = ((4 + quad) ^ (m15 & 7)) * 16;

    floatx4 acc[4][4];
#pragma unroll
    for (int i = 0; i < 4; ++i)
#pragma unroll
        for (int j = 0; j < 4; ++j) acc[i][j] = (floatx4)0.f;

    bf16x8 afc[2][4];   // s0 A-frag cache -> s1 (one dy live)
    bf16x8 bfc[2][4];   // s0 B-frag cache -> s2 (one dy live)

    if (aInt && bInt) {
        // chunk issue ids: c1 Ah0, c2 Ah1, c3 Bh0, c4 Bh1, c5 Ah2, c6 Bh2,
        // c7 Ah3, c8 Bl0, c9 Bl1, c10 Al0 | t1: c11 Al1, c12 Bl2 | t2: c13 Bh3
        // t3: c14 Al2 | t4: c15 Bl3 | t5: c16 Al3.   (2 loads/thread/chunk)
        ISSUE_A(0, 0, 0); ISSUE_A(1, 0, 1); ISSUE_B(0, 0, 0); ISSUE_B(1, 0, 1);
        ISSUE_A(2, 0, 2); ISSUE_B(2, 0, 2); ISSUE_A(3, 0, 3); ISSUE_B(0, 1, 3);
        ISSUE_B(1, 1, 4); ISSUE_A(0, 2, 4);
        PBAR(12);                                      STEP_S0(0);  // needs c1-c4
        PBAR(2);  ISSUE_A(1, 2, 0); ISSUE_B(2, 1, 0); STEP_S1(0);  // needs c8,c9
        PBAR(2);  ISSUE_B(3, 0, 3);                   STEP_S2(0);  // needs c10,c11
        PBAR(14); ISSUE_A(2, 2, 4);                   STEP_S0(1);  // needs c2,c4,c5,c6
        PBAR(4);  ISSUE_B(3, 1, 1);                   STEP_S1(1);  // needs c9,c12
        PBAR(2);  ISSUE_A(3, 2, 1);                   STEP_S2(1);  // needs c11,c14
        PBAR(6);                                      STEP_S0(2);  // needs c5,c6,c7,c13
        PBAR(2);                                      STEP_S1(2);  // needs c12,c15
        PBAR(0);                                      STEP_S2(2);  // needs c14,c16
        __syncthreads();   // slabs dead before epilogue overwrites
    } else {
        // ---- legacy guarded path (boundary blocks): stage full slabs per seg ----
        for (int seg = 0; seg < 3; ++seg) {
            const char* abL = Aqb + (size_t)(q0 - 64) * 384 + seg * 128;
            const char* bbL = Bqb + (size_t)(k0 - 64) * 384 + seg * 128;
            if (aInt) {
#pragma unroll
                for (int it = 0; it < 8; ++it) {
                    int slot = it * 256 + tid;
                    int row = slot >> 3, pos = slot & 7;
                    int G = pos ^ (row & 7);
                    gload_lds16(abL + (size_t)row * 384 + G * 16, smem + slot * 16);
                }
            } else {
#pragma unroll
                for (int it = 0; it < 8; ++it) {
                    int slot = it * 256 + tid;
                    int row = slot >> 3, pos = slot & 7;
                    int G = pos ^ (row & 7);
                    uint4 v = make_uint4(0u, 0u, 0u, 0u);
                    if ((unsigned)(q0 - 64 + row) < 4096u)
                        v = *(const uint4*)(abL + (size_t)row * 384 + G * 16);
                    *(uint4*)(smem + slot * 16) = v;
                }
            }
            if (bInt) {
#pragma unroll
                for (int it = 0; it < 8; ++it) {
                    int slot = it * 256 + tid;
                    int row = slot >> 3, pos = slot & 7;
                    int G = pos ^ (row & 7);
                    gload_lds16(bbL + (size_t)row * 384 + G * 16, smemB + slot * 16);
                }
            } else {
#pragma unroll
                for (int it = 0; it < 8; ++it) {
                    int slot = it * 256 + tid;
                    int row = slot >> 3, pos = slot & 7;
                    int G = pos ^ (row & 7);
                    uint4 v = make_uint4(0u, 0u, 0u, 0u);
                    if ((unsigned)(k0 - 64 + row) < 4096u)
                        v = *(const uint4*)(bbL + (size_t)row * 384 + G * 16);
                    *(uint4*)(smemB + slot * 16) = v;
                }
            }
            __syncthreads();
            STEP_S0(0); STEP_S0(1); STEP_S0(2);
            __syncthreads();
        }
    }

    // ---- epilogue: two 64-row phases; x-3sum + max/argmax over the 128-k tile,
    // then cross-quarter LDS reduce -> one partial per (block, q) ----
    float* Csh = (float*)smem;               // [64][133]
    float* bvs = (float*)(smem + 34816);     // [4][64]
    int*   bas = (int*)(smem + 35840);       // [4][64]
    const int q_l = tid & 63;
    const int qr = tid >> 6;                 // k-quarter (0..3), one per wave
    const int c0 = qr * 32;
    const float4 zero4 = make_float4(0.f, 0.f, 0.f, 0.f);

#pragma unroll
    for (int h = 0; h < 2; ++h) {
        if (h) __syncthreads();              // phase-0 readers done before overwrite
        if (wm == h) {
#pragma unroll
            for (int mt = 0; mt < 4; ++mt)
#pragma unroll
                for (int nt = 0; nt < 4; ++nt)
#pragma unroll
                    for (int j = 0; j < 4; ++j)
                        Csh[(mt * 16 + quad * 4 + j) * 133 + wn * 64 + nt * 16 + m15] =
                            acc[mt][nt][j];
        }
        __syncthreads();

        const bool qm = q_l > 0;             // qx>0: diag- allowed
        const bool qp = q_l < 63;            // qx<63: diag+ allowed
        const float* rC = Csh + q_l * 133;
        const float* rM = Csh + (q_l - 1) * 133;
        const float* rP = Csh + (q_l + 1) * 133;
        float4 prevm = (qm && c0 > 0) ? *(const float4*)&rM[c0 - 4] : zero4;
        float4 rpj   = qp ? *(const float4*)&rP[c0] : zero4;
        float bv = -INFINITY;
        int ba = 0;
#pragma unroll
        for (int j = 0; j < 8; ++j) {
            int c = c0 + 4 * j;
            float4 cen = *(const float4*)&rC[c];
            float4 rm4 = qm ? *(const float4*)&rM[c] : zero4;
            float4 rp1 = (qp && (c + 4) < 128) ? *(const float4*)&rP[c + 4] : zero4;
            float4 o4;
            o4.x = cen.x + (((c & 63) != 0) ? prevm.w : 0.f) + rpj.y;
            o4.y = cen.y + rm4.x + rpj.z;
            o4.z = cen.z + rm4.y + rpj.w;
            o4.w = cen.w + rm4.z + ((((c + 3) & 63) != 63) ? rp1.x : 0.f);
            float4 rk = *(const float4*)&rnkA[(b << 12) + k0 + c];
            // ascending k + strict > = first-occurrence argmax
            float v0 = o4.x * rk.x; if (v0 > bv) { bv = v0; ba = k0 + c + 0; }
            float v1 = o4.y * rk.y; if (v1 > bv) { bv = v1; ba = k0 + c + 1; }
            float v2 = o4.z * rk.z; if (v2 > bv) { bv = v2; ba = k0 + c + 2; }
            float v3 = o4.w * rk.w; if (v3 > bv) { bv = v3; ba = k0 + c + 3; }
            prevm = rm4;
            rpj = rp1;
        }
        bvs[(qr << 6) + q_l] = bv;
        bas[(qr << 6) + q_l] = ba;
        __syncthreads();
        if (tid < 64) {
            float v = bvs[tid];
            int a = bas[tid];
#pragma unroll
            for (int s = 1; s < 4; ++s) {    // ascending quarter = ascending k
                float v2 = bvs[(s << 6) + tid];
                if (v2 > v) { v = v2; a = bas[(s << 6) + tid]; }
            }
            int q = q0 + h * 64 + tid;
            part_val[(((b << 5) + kt) << 12) + q] = v;
            part_arg[(((b << 5) + kt) << 12) + q] = a;
        }
    }
}

// ---------------- combine 32 k-slot partials -> final arg + S ----------------
__global__ __launch_bounds__(256)
void argcombine_kernel(const float* __restrict__ part_val, const int* __restrict__ part_arg,
                       const float* __restrict__ rnqA,
                       float* __restrict__ S_out, int* __restrict__ argF) {
    __shared__ float rv[4][64];
    __shared__ int ra[4][64];
    const int tid = threadIdx.x;
    const int qi = tid & 63, sg = tid >> 6;
    const int q = blockIdx.x * 64 + qi;
    const int b = blockIdx.y;
    const int base = (b << 17) + q;
    float bv = -INFINITY; int ba = 0;
#pragma unroll
    for (int s8 = 0; s8 < 8; ++s8) {         // ascending s = ascending k
        int s = sg * 8 + s8;
        float v = part_val[base + (s << 12)];
        int aa = part_arg[base + (s << 12)];
        if (v > bv) { bv = v; ba = aa; }
    }
    rv[sg][qi] = bv; ra[sg][qi] = ba;
    __syncthreads();
    if (tid < 64) {
        float v = rv[0][tid]; int a = ra[0][tid];
#pragma unroll
        for (int s = 1; s < 4; ++s) {        // ascending group: first max wins
            float v2 = rv[s][tid];
            if (v2 > v) { v = v2; a = ra[s][tid]; }
        }
        int idx = (b << 12) + blockIdx.x * 64 + tid;
        S_out[idx] = v * rnqA[idx];
        argF[idx] = a;
    }
}

// ---------------- gather + fold: T[c,y,x] = (1/9) sum_9 VT[a(q)+d][c] --------
// VT is [b][p][c] so one patch-offset's channels are CONTIGUOUS: thread
// (x, cq) loads float4 of 4 channels; 4 lanes sharing x hit one 64B segment.
// ~16x fewer L2 lines than the [c][p] scalar gather.
__global__ __launch_bounds__(256)
void gatherT_kernel(const float* __restrict__ VT, const int* __restrict__ argF,
                    float* __restrict__ T_out) {
    __shared__ int sArg[192];
    const int y = blockIdx.x, b = blockIdx.y, cg = blockIdx.z;
    const int tid = threadIdx.x;
    if (tid < 192) {
        int r = tid >> 6, x = tid & 63;
        int yy = y - 1 + r;
        sArg[tid] = ((unsigned)yy < 64u) ? argF[(b << 12) + (yy << 6) + x] : 0;
    }
    __syncthreads();

    const int x = tid >> 2, cq = tid & 3;
    const float* Vb = VT + (size_t)b * 4096 * 64 + cg * 16 + cq * 4;
    float ax = 0.f, ay = 0.f, az = 0.f, aw = 0.f;
#pragma unroll
    for (int t = 0; t < 9; ++t) {
        int dy = t / 3 - 1, dx = t % 3 - 1;
        int qy = y - dy, qx = x - dx;
        if ((unsigned)qy < 64u && (unsigned)qx < 64u) {
            int a = sArg[(1 - dy) * 64 + qx];
            int sy = (a >> 6) + dy, sx = (a & 63) + dx;
            if ((unsigned)sy < 64u && (unsigned)sx < 64u) {
                float4 v = *(const float4*)(Vb + (size_t)((sy << 6) + sx) * 64);
                ax += v.x; ay += v.y; az += v.z; aw += v.w;
            }
        }
    }
    float* Tb = T_out + ((size_t)b * 64 + cg * 16 + cq * 4) * HW + (y << 6) + x;
    Tb[0]          = ax * (1.f / 9.f);
    Tb[HW]         = ay * (1.f / 9.f);
    Tb[2 * HW]     = az * (1.f / 9.f);
    Tb[3 * HW]     = aw * (1.f / 9.f);
}

extern "C" void kernel_launch(void* const* d_in, const int* in_sizes, int n_in,
                              void* d_out, int out_size, void* d_ws, size_t ws_size,
                              hipStream_t stream) {
    const float* V = (const float*)d_in[0];
    const float* K = (const float*)d_in[1];
    const float* Q = (const float*)d_in[2];
    float* S_out = (float*)d_out;            // 4*4096
    float* T_out = S_out + 4 * HW;           // 4*64*4096

    char* ws = (char*)d_ws;
    float* pix2q = (float*)(ws + 0);                 // 64 KB
    float* pix2k = (float*)(ws + 65536);
    float* rnq   = (float*)(ws + 131072);
    float* rnk   = (float*)(ws + 196608);
    float* part_val = (float*)(ws + 262144);         // 4*32*4096 f = 2 MB used
    int*   argF  = (int*)(ws + 4456448);             // 64 KB
    int*   part_arg = (int*)(ws + 8650752);          // 2 MB used
    float* VT    = (float*)(ws + 10747904);          // 4*4096*64 f32 = 4 MiB
    unsigned short* Aq = (unsigned short*)(ws + 17039360);   // 4*4096*192 bf16 = 6 MiB
    unsigned short* Bq = (unsigned short*)(ws + 23330816);   // 6 MiB

    prep_kernel<<<dim3(64, 4, 3), 256, 0, stream>>>(Q, K, V, Aq, Bq, VT, pix2q, pix2k);
    patchnorm_kernel<<<64, 256, 0, stream>>>(pix2q, pix2k, rnq, rnk);
    gemm_fused_kernel<<<dim3(32, 32, 4), 256, 0, stream>>>(Aq, Bq, rnk, part_val, part_arg);
    argcombine_kernel<<<dim3(64, 4), 256, 0, stream>>>(part_val, part_arg, rnq, S_out, argF);
    gatherT_kernel<<<dim3(64, 4, 4), 256, 0, stream>>>(VT, argF, T_out);
}